// Round 10
// baseline (280.278 us; speedup 1.0000x reference)
//
#include <hip/hip_runtime.h>
#include <hip/hip_bf16.h>
#include <math.h>

#define BB 16
#define CC 512
#define DD 64
#define NN 4096
#define EPSV 1e-6f

typedef __attribute__((ext_vector_type(8))) short short8;
typedef __attribute__((ext_vector_type(4))) short s16x4;
typedef __attribute__((ext_vector_type(4))) float f32x4;

__device__ __forceinline__ float softplus_f(float v) {
    return fmaxf(v, 0.0f) + log1pf(expf(-fabsf(v)));
}
__device__ __forceinline__ short bf16s(float f) {
    __hip_bfloat16 h = __float2bfloat16(f);
    return __builtin_bit_cast(short, h);
}
__device__ __forceinline__ float sbf16(short s) {
    return __bfloat162float(__builtin_bit_cast(__hip_bfloat16, s));
}

// ---- prep: Wcat bf16 [128][512] (blocks 0-255), zero KX (256-767), zero Ksum (768) ----
__global__ __launch_bounds__(256) void k_prep(const float* __restrict__ Wq,
                                              const float* __restrict__ Wk,
                                              __hip_bfloat16* __restrict__ Wcat,
                                              float* __restrict__ KX,
                                              float* __restrict__ Ksum) {
    int blk = blockIdx.x;
    if (blk < 256) {
        int i = blk * 256 + threadIdx.x;
        int j = i >> 9, c = i & 511;
        float v = (j < DD) ? Wq[j * CC + c] : Wk[(j - DD) * CC + c];
        Wcat[i] = __float2bfloat16(v);
    } else if (blk < 768) {
        int i = (blk - 256) * 256 + threadIdx.x;   // 512*256 f32x4 = 2MB
        f32x4 z = {0.f, 0.f, 0.f, 0.f};
        reinterpret_cast<f32x4*>(KX)[i] = z;
    } else {
        f32x4 z = {0.f, 0.f, 0.f, 0.f};
        reinterpret_cast<f32x4*>(Ksum)[threadIdx.x] = z;  // 1024 floats
    }
}

// ==== ABLATION: round-8 staging loop ONLY (x loads + W gathers + LDS writes +
//      barriers), x2 reps, no MFMA / no epilogue. Checksum defeats DCE. ====
__global__ __launch_bounds__(256) void k_ab_stage(const float* __restrict__ x,
                                                  const __hip_bfloat16* __restrict__ Wcat,
                                                  float* __restrict__ dummy) {
    __shared__ unsigned short xs[2][128][40];
    int b = blockIdx.y;
    int n_blk = blockIdx.x * 128;
    int t = threadIdx.x;
    int lane = t & 63;
    int l16 = lane & 15, g = lane >> 4;
    int sn = t & 127;
    int sc16 = (t >> 7) * 16;
    const float* xb = x + (size_t)b * CC * NN + n_blk + sn;
    const short8* wp = reinterpret_cast<const short8*>(Wcat);
    float xr[16];
    short8 wA[8];
    float acc = 0.f;
#pragma unroll 1
    for (int rep = 0; rep < 2; ++rep) {
#pragma unroll 1
        for (int ck = 0; ck < 16; ++ck) {
#pragma unroll
            for (int i = 0; i < 16; ++i)
                xr[i] = xb[(size_t)(ck * 32 + sc16 + i) * NN];
#pragma unroll
            for (int jf = 0; jf < 8; ++jf)
                wA[jf] = wp[(size_t)(jf * 16 + l16) * 64 + ck * 4 + g];
            __syncthreads();
            int bi = ck & 1;
#pragma unroll
            for (int i = 0; i < 4; ++i) {
                s16x4 pv;
#pragma unroll
                for (int j2 = 0; j2 < 4; ++j2) pv[j2] = bf16s(xr[i * 4 + j2]);
                *reinterpret_cast<s16x4*>(&xs[bi][sn][sc16 + i * 4]) = pv;
            }
            __syncthreads();
            acc += sbf16((short)xs[bi][(t + 1) & 127][(t >> 3) & 31]);
#pragma unroll
            for (int jf = 0; jf < 8; ++jf) acc += sbf16(wA[jf][0]);
        }
    }
    dummy[((size_t)blockIdx.y * gridDim.x + blockIdx.x) * 256 + t] = acc;
}

// ---- Q/K projection via MFMA (round-8 main loop, UNCHANGED) + LDS-bounced
//      coalesced epilogue writes. Qb[b][n][d] bf16 ; Kb[b][m][n] bf16 ----
__global__ __launch_bounds__(256) void k_proj(const float* __restrict__ x,
                                              const __hip_bfloat16* __restrict__ Wcat,
                                              const float* __restrict__ bq,
                                              const float* __restrict__ bk,
                                              __hip_bfloat16* __restrict__ Qb,
                                              __hip_bfloat16* __restrict__ Kb,
                                              float* __restrict__ Ksum) {
    __shared__ unsigned short xs[2][128][40];   // staging; reused for epilogue tiles

    int b = blockIdx.y;
    int n_blk = blockIdx.x * 128;
    int t = threadIdx.x;
    int wave = t >> 6, lane = t & 63;
    int nwl = wave * 32;
    int l16 = lane & 15, g = lane >> 4;

    int sn = t & 127;
    int sc16 = (t >> 7) * 16;
    const float* xb = x + (size_t)b * CC * NN + n_blk + sn;
    const short8* wp = reinterpret_cast<const short8*>(Wcat);

    float xr[16];
    auto loadx = [&](int c0) {
#pragma unroll
        for (int i = 0; i < 16; ++i)
            xr[i] = xb[(size_t)(c0 + sc16 + i) * NN];
    };
    auto writex = [&](int bi) {
#pragma unroll
        for (int i = 0; i < 4; ++i) {
            s16x4 pv;
#pragma unroll
            for (int j = 0; j < 4; ++j) pv[j] = bf16s(xr[i * 4 + j]);
            *reinterpret_cast<s16x4*>(&xs[bi][sn][sc16 + i * 4]) = pv;
        }
    };

    short8 wA[8], wB[8];
    f32x4 accQ[2][4] = {};
    f32x4 accK[4][2] = {};

#define LOADW(dst, ck)                                                        \
    {                                                                         \
        _Pragma("unroll")                                                     \
        for (int jf = 0; jf < 8; ++jf)                                        \
            dst[jf] = wp[(size_t)(jf * 16 + l16) * 64 + (ck) * 4 + g];        \
    }

#define DO_MFMA(wreg, cur)                                                    \
    {                                                                         \
        short8 xf[2];                                                         \
        _Pragma("unroll")                                                     \
        for (int nf = 0; nf < 2; ++nf)                                        \
            xf[nf] = *reinterpret_cast<const short8*>(                        \
                &xs[cur][nwl + nf * 16 + l16][g * 8]);                        \
        _Pragma("unroll")                                                     \
        for (int nf = 0; nf < 2; ++nf)                                        \
            _Pragma("unroll")                                                 \
            for (int jf = 0; jf < 4; ++jf)                                    \
                accQ[nf][jf] = __builtin_amdgcn_mfma_f32_16x16x32_bf16(       \
                    xf[nf], wreg[jf], accQ[nf][jf], 0, 0, 0);                 \
        _Pragma("unroll")                                                     \
        for (int jf = 0; jf < 4; ++jf)                                        \
            _Pragma("unroll")                                                 \
            for (int nf = 0; nf < 2; ++nf)                                    \
                accK[jf][nf] = __builtin_amdgcn_mfma_f32_16x16x32_bf16(       \
                    wreg[4 + jf], xf[nf], accK[jf][nf], 0, 0, 0);             \
    }

    loadx(0);
    LOADW(wA, 0);
    writex(0);

#pragma unroll 1
    for (int ck2 = 0; ck2 < 8; ++ck2) {
        int ck = ck2 * 2;
        loadx((ck + 1) * 32);
        LOADW(wB, ck + 1);
        __syncthreads();
        DO_MFMA(wA, 0);
        writex(1);
        if (ck2 < 7) {
            loadx((ck + 2) * 32);
            LOADW(wA, ck + 2);
        }
        __syncthreads();
        DO_MFMA(wB, 1);
        if (ck2 < 7) writex(0);
    }
#undef LOADW
#undef DO_MFMA

    // ---- epilogue: K tile -> LDS [64][132] -> coalesced 256B-row writes ----
    unsigned short* kt = &xs[0][0][0];          // 64*132*2 = 16896 B <= 20480
    __syncthreads();                            // xs reads done before overwrite
#pragma unroll
    for (int jf = 0; jf < 4; ++jf)
#pragma unroll
        for (int r = 0; r < 4; ++r) {
            int m = jf * 16 + 4 * g + r;
            float s = 0.f;
#pragma unroll
            for (int nf = 0; nf < 2; ++nf) {
                int nl = nwl + nf * 16 + l16;
                float v = softplus_f(accK[jf][nf][r] + bk[m]);
                kt[m * 132 + nl] = (unsigned short)bf16s(v);
                s += v;
            }
            s += __shfl_xor(s, 1, 64);
            s += __shfl_xor(s, 2, 64);
            s += __shfl_xor(s, 4, 64);
            s += __shfl_xor(s, 8, 64);
            if (l16 == 0) atomicAdd(&Ksum[b * DD + m], s);
        }
    __syncthreads();
    {
        int mrow = t >> 4;                      // 0..15
        int seg = t & 15;                       // 16B segment of 256B row
#pragma unroll
        for (int pass = 0; pass < 4; ++pass) {
            int m = pass * 16 + mrow;
            short8 v = *reinterpret_cast<const short8*>(&kt[m * 132 + seg * 8]);
            *reinterpret_cast<short8*>(&Kb[((size_t)(b * DD + m)) * NN + n_blk + seg * 8]) = v;
        }
    }
    __syncthreads();
    // ---- Q tile -> LDS [128][68] -> coalesced 128B-row writes ----
    unsigned short* qt = kt;                    // 128*68*2 = 17408 B <= 20480
#pragma unroll
    for (int nf = 0; nf < 2; ++nf)
#pragma unroll
        for (int jf = 0; jf < 4; ++jf)
#pragma unroll
            for (int r = 0; r < 4; ++r) {
                int nl = nwl + nf * 16 + 4 * g + r;
                int j = jf * 16 + l16;
                float v = softplus_f(accQ[nf][jf][r] + bq[j]);
                qt[nl * 68 + j] = (unsigned short)bf16s(v);
            }
    __syncthreads();
    {
        int nrow = t >> 3;                      // 0..31
        int seg = t & 7;                        // 16B segment of 128B row
#pragma unroll
        for (int pass = 0; pass < 4; ++pass) {
            int nl = pass * 32 + nrow;
            short8 v = *reinterpret_cast<const short8*>(&qt[nl * 68 + seg * 8]);
            *reinterpret_cast<short8*>(&Qb[((size_t)b * NN + n_blk + nl) * DD + seg * 8]) = v;
        }
    }
}

// ---- KX[b][m][c] += sum_nn Kb[m][nn]*x[c][nn]  (MFMA, no LDS, split-K atomics) ----
__global__ __launch_bounds__(256) void k_kx(const __hip_bfloat16* __restrict__ Kb,
                                            const float* __restrict__ x,
                                            float* __restrict__ KX) {
    int b = blockIdx.z;
    int n0 = blockIdx.y * 256;                // 16 n-chunks
    int c0 = blockIdx.x * 256;                // 2 c-halves
    int wave = threadIdx.x >> 6, lane = threadIdx.x & 63;
    int cw = c0 + wave * 64;                  // wave owns 64 c-cols
    int l16 = lane & 15, g = lane >> 4;

    f32x4 acc[4][4] = {};                     // [mi][cj]
    const __hip_bfloat16* kp = Kb + (size_t)b * DD * NN;
    const float* xp = x + (size_t)b * CC * NN;

#pragma unroll
    for (int ks = 0; ks < 8; ++ks) {          // 256 n in steps of 32
        int nk = n0 + ks * 32 + g * 8;
        short8 af[4];
#pragma unroll
        for (int mi = 0; mi < 4; ++mi)
            af[mi] = *reinterpret_cast<const short8*>(kp + (size_t)(mi * 16 + l16) * NN + nk);
        short8 bf[4];
#pragma unroll
        for (int cj = 0; cj < 4; ++cj) {
            const float* xr = xp + (size_t)(cw + cj * 16 + l16) * NN + nk;
            f32x4 lo = *reinterpret_cast<const f32x4*>(xr);
            f32x4 hi = *reinterpret_cast<const f32x4*>(xr + 4);
            short8 v;
#pragma unroll
            for (int e = 0; e < 4; ++e) { v[e] = bf16s(lo[e]); v[4 + e] = bf16s(hi[e]); }
            bf[cj] = v;
        }
#pragma unroll
        for (int mi = 0; mi < 4; ++mi)
#pragma unroll
            for (int cj = 0; cj < 4; ++cj)
                acc[mi][cj] = __builtin_amdgcn_mfma_f32_16x16x32_bf16(af[mi], bf[cj], acc[mi][cj], 0, 0, 0);
    }
#pragma unroll
    for (int mi = 0; mi < 4; ++mi)
#pragma unroll
        for (int cj = 0; cj < 4; ++cj)
#pragma unroll
            for (int r = 0; r < 4; ++r) {
                int m = mi * 16 + 4 * g + r;
                int c = cw + cj * 16 + l16;
                atomicAdd(&KX[((size_t)(b * DD + m)) * CC + c], acc[mi][cj][r]);
            }
}

// ---- KVTb[b][c][m] = sum_cp KX[b][m][cp]*Wv[c][cp] + bv[c]*Ksum[b][m]
//      MFMA, no LDS, split hi/lo bf16 for ~fp32 accuracy. ----
__global__ __launch_bounds__(256) void k_kv(const float* __restrict__ KX,
                                            const float* __restrict__ Wv,
                                            const float* __restrict__ bv,
                                            const float* __restrict__ Ksum,
                                            __hip_bfloat16* __restrict__ KVTb) {
    int b = blockIdx.y;
    int c0 = blockIdx.x * 64;
    int wave = threadIdx.x >> 6, lane = threadIdx.x & 63;
    int cw = c0 + wave * 16;                  // wave owns 16 c-rows, all 64 m
    int l16 = lane & 15, g = lane >> 4;

    f32x4 acc[4] = {};                        // [mj]
    const float* wvp = Wv + (size_t)(cw + l16) * CC;
    const float* kxp = KX + (size_t)b * DD * CC;

#pragma unroll
    for (int ck = 0; ck < 16; ++ck) {         // 512 cp in steps of 32
        int cp = ck * 32 + g * 8;
        f32x4 w0 = *reinterpret_cast<const f32x4*>(wvp + cp);
        f32x4 w1 = *reinterpret_cast<const f32x4*>(wvp + cp + 4);
        short8 a_hi, a_lo;
#pragma unroll
        for (int e = 0; e < 4; ++e) {
            a_hi[e] = bf16s(w0[e]);     a_lo[e] = bf16s(w0[e] - sbf16(a_hi[e]));
            a_hi[4 + e] = bf16s(w1[e]); a_lo[4 + e] = bf16s(w1[e] - sbf16(a_hi[4 + e]));
        }
#pragma unroll
        for (int mj = 0; mj < 4; ++mj) {
            const float* kr = kxp + (size_t)(mj * 16 + l16) * CC + cp;
            f32x4 k0 = *reinterpret_cast<const f32x4*>(kr);
            f32x4 k1 = *reinterpret_cast<const f32x4*>(kr + 4);
            short8 b_hi, b_lo;
#pragma unroll
            for (int e = 0; e < 4; ++e) {
                b_hi[e] = bf16s(k0[e]);     b_lo[e] = bf16s(k0[e] - sbf16(b_hi[e]));
                b_hi[4 + e] = bf16s(k1[e]); b_lo[4 + e] = bf16s(k1[e] - sbf16(b_hi[4 + e]));
            }
            acc[mj] = __builtin_amdgcn_mfma_f32_16x16x32_bf16(a_hi, b_hi, acc[mj], 0, 0, 0);
            acc[mj] = __builtin_amdgcn_mfma_f32_16x16x32_bf16(a_lo, b_hi, acc[mj], 0, 0, 0);
            acc[mj] = __builtin_amdgcn_mfma_f32_16x16x32_bf16(a_hi, b_lo, acc[mj], 0, 0, 0);
        }
    }
#pragma unroll
    for (int mj = 0; mj < 4; ++mj)
#pragma unroll
        for (int r = 0; r < 4; ++r) {
            int c = cw + 4 * g + r;
            int m = mj * 16 + l16;
            KVTb[((size_t)b * CC + c) * DD + m] =
                __float2bfloat16(acc[mj][r] + bv[c] * Ksum[b * DD + m]);
        }
}

// ---- out[c][n] = x + (gamma/dot(Q[n],Ksum+eps)) * sum_m KVT[c][m]*Q[n][m]
//      MFMA K=64, norm fused in-register ----
__global__ __launch_bounds__(256) void k_out(const float* __restrict__ x,
                                             const __hip_bfloat16* __restrict__ Qb,
                                             const __hip_bfloat16* __restrict__ KVTb,
                                             const float* __restrict__ Ksum,
                                             const float* __restrict__ gamma,
                                             float* __restrict__ out) {
    int b = blockIdx.z;
    int c_blk = blockIdx.x * 128, n_blk = blockIdx.y * 128;
    int wave = threadIdx.x >> 6, lane = threadIdx.x & 63;
    int cw = c_blk + (wave >> 1) * 64, nw = n_blk + (wave & 1) * 64;
    int l16 = lane & 15, g = lane >> 4;

    float ksv[2][8];
#pragma unroll
    for (int ck = 0; ck < 2; ++ck)
#pragma unroll
        for (int e = 0; e < 8; ++e)
            ksv[ck][e] = Ksum[b * DD + (ck * 4 + g) * 8 + e] + EPSV;

    f32x4 acc[4][4] = {};
    float dot[4] = {0.f, 0.f, 0.f, 0.f};
    const short8* ap = reinterpret_cast<const short8*>(KVTb) + ((size_t)b * CC + cw) * 8;
    const short8* bp = reinterpret_cast<const short8*>(Qb) + ((size_t)b * NN + nw) * 8;
#pragma unroll
    for (int ck = 0; ck < 2; ++ck) {
        int ch = ck * 4 + g;
        short8 af[4], bf[4];
#pragma unroll
        for (int i = 0; i < 4; ++i) af[i] = ap[(size_t)(i * 16 + l16) * 8 + ch];
#pragma unroll
        for (int i = 0; i < 4; ++i) bf[i] = bp[(size_t)(i * 16 + l16) * 8 + ch];
#pragma unroll
        for (int j = 0; j < 4; ++j)
#pragma unroll
            for (int e = 0; e < 8; ++e)
                dot[j] = fmaf(sbf16(bf[j][e]), ksv[ck][e], dot[j]);
#pragma unroll
        for (int i = 0; i < 4; ++i)
#pragma unroll
            for (int j = 0; j < 4; ++j)
                acc[i][j] = __builtin_amdgcn_mfma_f32_16x16x32_bf16(af[i], bf[j], acc[i][j], 0, 0, 0);
    }
    float gm = gamma[0];
    float sc[4];
#pragma unroll
    for (int j = 0; j < 4; ++j) {
        float d = dot[j];
        d += __shfl_xor(d, 16, 64);
        d += __shfl_xor(d, 32, 64);
        sc[j] = gm / d;
    }
    const float* xb = x + (size_t)b * CC * NN;
    float* ob = out + (size_t)b * CC * NN;
#pragma unroll
    for (int i = 0; i < 4; ++i)
#pragma unroll
        for (int r = 0; r < 4; ++r) {
            int c = cw + i * 16 + 4 * g + r;
            size_t rowoff = (size_t)c * NN;
#pragma unroll
            for (int j = 0; j < 4; ++j) {
                int n = nw + j * 16 + l16;
                ob[rowoff + n] = xb[rowoff + n] + sc[j] * acc[i][j][r];
            }
        }
}

extern "C" void kernel_launch(void* const* d_in, const int* in_sizes, int n_in,
                              void* d_out, int out_size, void* d_ws, size_t ws_size,
                              hipStream_t stream) {
    const float* x     = (const float*)d_in[0];
    const float* Wq    = (const float*)d_in[1];
    const float* bq    = (const float*)d_in[2];
    const float* Wk    = (const float*)d_in[3];
    const float* bk    = (const float*)d_in[4];
    const float* Wv    = (const float*)d_in[5];
    const float* bv    = (const float*)d_in[6];
    const float* gamma = (const float*)d_in[7];
    float* out = (float*)d_out;

    float* ws    = (float*)d_ws;
    float* KX    = ws;                                   // B*D*C fp32 (2MB)
    float* Ksum  = KX + (size_t)BB * DD * CC;            // B*D fp32
    __hip_bfloat16* Qb   = (__hip_bfloat16*)(Ksum + BB * DD);  // B*N*D bf16
    __hip_bfloat16* Kb   = Qb + (size_t)BB * NN * DD;    // B*D*N bf16
    __hip_bfloat16* KVTb = Kb + (size_t)BB * DD * NN;    // B*C*D bf16
    __hip_bfloat16* Wcat = KVTb + (size_t)BB * CC * DD;  // 128*C bf16
    float* dummy = (float*)(Wcat + 128 * CC);            // 512KB ablation sink

    k_prep<<<dim3(769), dim3(256), 0, stream>>>(Wq, Wk, Wcat, KX, Ksum);
    k_proj<<<dim3(NN / 128, BB), dim3(256), 0, stream>>>(x, Wcat, bq, bk, Qb, Kb, Ksum);
    k_kx<<<dim3(2, 16, BB), dim3(256), 0, stream>>>(Kb, x, KX);
    k_kv<<<dim3(CC / 64, BB), dim3(256), 0, stream>>>(KX, Wv, bv, Ksum, KVTb);
    k_out<<<dim3(CC / 128, NN / 128, BB), dim3(256), 0, stream>>>(x, Qb, KVTb, Ksum, gamma, out);
    // diagnostic last: staging-only x2 (read per-dispatch dur in rocprof, /2)
    k_ab_stage<<<dim3(NN / 128, BB), dim3(256), 0, stream>>>(x, Wcat, dummy);
}

// Round 11
// 246.892 us; speedup vs baseline: 1.1352x; 1.1352x over previous
//
#include <hip/hip_runtime.h>
#include <hip/hip_bf16.h>
#include <math.h>

#define BB 16
#define CC 512
#define DD 64
#define NN 4096
#define EPSV 1e-6f

typedef __attribute__((ext_vector_type(8))) short short8;
typedef __attribute__((ext_vector_type(4))) float f32x4;

__device__ __forceinline__ float softplus_f(float v) {
    return fmaxf(v, 0.0f) + log1pf(expf(-fabsf(v)));
}
__device__ __forceinline__ short bf16s(float f) {
    __hip_bfloat16 h = __float2bfloat16(f);
    return __builtin_bit_cast(short, h);
}
__device__ __forceinline__ float sbf16(short s) {
    return __bfloat162float(__builtin_bit_cast(__hip_bfloat16, s));
}

// ---- prep: Wcat bf16 [128][512] (blocks 0-255), zero KX (256-767), zero Ksum (768) ----
__global__ __launch_bounds__(256) void k_prep(const float* __restrict__ Wq,
                                              const float* __restrict__ Wk,
                                              __hip_bfloat16* __restrict__ Wcat,
                                              float* __restrict__ KX,
                                              float* __restrict__ Ksum) {
    int blk = blockIdx.x;
    if (blk < 256) {
        int i = blk * 256 + threadIdx.x;
        int j = i >> 9, c = i & 511;
        float v = (j < DD) ? Wq[j * CC + c] : Wk[(j - DD) * CC + c];
        Wcat[i] = __float2bfloat16(v);
    } else if (blk < 768) {
        int i = (blk - 256) * 256 + threadIdx.x;   // 512*256 f32x4 = 2MB
        f32x4 z = {0.f, 0.f, 0.f, 0.f};
        reinterpret_cast<f32x4*>(KX)[i] = z;
    } else {
        f32x4 z = {0.f, 0.f, 0.f, 0.f};
        reinterpret_cast<f32x4*>(Ksum)[threadIdx.x] = z;  // 1024 floats
    }
}

// ---- prep: xt[b][n][c] bf16 (transpose of x) — pure streaming, measured fast (r2) ----
__global__ __launch_bounds__(256) void k_xt(const float* __restrict__ x,
                                            __hip_bfloat16* __restrict__ xt) {
    int b = blockIdx.z;
    int n0 = blockIdx.x * 64, c0 = blockIdx.y * 64;
    __shared__ float tile[64][65];
    const float* xb = x + ((size_t)b * CC + c0) * NN + n0;
    int t = threadIdx.x;
#pragma unroll
    for (int i = 0; i < 16; ++i) {
        int idx = i * 256 + t;
        int c = idx >> 6, n = idx & 63;
        tile[c][n] = xb[(size_t)c * NN + n];
    }
    __syncthreads();
    __hip_bfloat16* xo = xt + ((size_t)b * NN + n0) * CC + c0;
#pragma unroll
    for (int i = 0; i < 16; ++i) {
        int idx = i * 256 + t;
        int n = idx >> 6, c = idx & 63;
        xo[(size_t)n * CC + c] = __float2bfloat16(tile[c][n]);
    }
}

// ---- Q/K projection via MFMA from xt (round-2 structure: measured fast).
//      Fused Ksum. Qb[b][n][d] bf16 ; Kb[b][m][n] bf16 ----
__global__ __launch_bounds__(256) void k_proj(const __hip_bfloat16* __restrict__ xt,
                                              const __hip_bfloat16* __restrict__ Wcat,
                                              const float* __restrict__ bq,
                                              const float* __restrict__ bk,
                                              __hip_bfloat16* __restrict__ Qb,
                                              __hip_bfloat16* __restrict__ Kb,
                                              float* __restrict__ Ksum) {
    int b = blockIdx.y;
    int n_blk = blockIdx.x * 128;
    int wave = threadIdx.x >> 6;
    int lane = threadIdx.x & 63;
    int n_wave = n_blk + wave * 32;           // wave owns 32 n-rows
    int l16 = lane & 15, g = lane >> 4;

    f32x4 accQ[2][4] = {};                    // D[n][j], j in [0,64)
    f32x4 accK[4][2] = {};                    // D[j][n], j in [64,128)

    const short8* xtp = reinterpret_cast<const short8*>(xt) + ((size_t)b * NN + n_wave) * 64;
    const short8* wp  = reinterpret_cast<const short8*>(Wcat);

    for (int ck = 0; ck < 16; ++ck) {         // 512 c in steps of 32
        int ch = ck * 4 + g;                  // 8-elem chunk index
        short8 xf[2], wf[8];
#pragma unroll
        for (int nf = 0; nf < 2; ++nf) xf[nf] = xtp[(size_t)(nf * 16 + l16) * 64 + ch];
#pragma unroll
        for (int jf = 0; jf < 8; ++jf) wf[jf] = wp[(size_t)(jf * 16 + l16) * 64 + ch];
#pragma unroll
        for (int nf = 0; nf < 2; ++nf)
#pragma unroll
            for (int jf = 0; jf < 4; ++jf)
                accQ[nf][jf] = __builtin_amdgcn_mfma_f32_16x16x32_bf16(xf[nf], wf[jf], accQ[nf][jf], 0, 0, 0);
#pragma unroll
        for (int jf = 0; jf < 4; ++jf)
#pragma unroll
            for (int nf = 0; nf < 2; ++nf)
                accK[jf][nf] = __builtin_amdgcn_mfma_f32_16x16x32_bf16(wf[4 + jf], xf[nf], accK[jf][nf], 0, 0, 0);
    }
    // Q epilogue: row n = n_wave + nf*16 + 4g + r, col j = jf*16 + l16
#pragma unroll
    for (int nf = 0; nf < 2; ++nf)
#pragma unroll
        for (int jf = 0; jf < 4; ++jf)
#pragma unroll
            for (int r = 0; r < 4; ++r) {
                int n = n_wave + nf * 16 + 4 * g + r;
                int j = jf * 16 + l16;
                float v = softplus_f(accQ[nf][jf][r] + bq[j]);
                Qb[((size_t)b * NN + n) * DD + j] = __float2bfloat16(v);
            }
    // K epilogue: row m = jf*16 + 4g + r, col n = n_wave + nf*16 + l16; fused Ksum
#pragma unroll
    for (int jf = 0; jf < 4; ++jf)
#pragma unroll
        for (int r = 0; r < 4; ++r) {
            int m = jf * 16 + 4 * g + r;
            float s = 0.f;
#pragma unroll
            for (int nf = 0; nf < 2; ++nf) {
                int n = n_wave + nf * 16 + l16;
                float v = softplus_f(accK[jf][nf][r] + bk[m]);
                Kb[((size_t)b * DD + m) * NN + n] = __float2bfloat16(v);
                s += v;
            }
            s += __shfl_xor(s, 1, 64);
            s += __shfl_xor(s, 2, 64);
            s += __shfl_xor(s, 4, 64);
            s += __shfl_xor(s, 8, 64);
            if (l16 == 0) atomicAdd(&Ksum[b * DD + m], s);
        }
}

// ---- KX[b][m][c] += sum_nn Kb[m][nn]*x[c][nn]  (MFMA, no LDS, split-K atomics) ----
__global__ __launch_bounds__(256) void k_kx(const __hip_bfloat16* __restrict__ Kb,
                                            const float* __restrict__ x,
                                            float* __restrict__ KX) {
    int b = blockIdx.z;
    int n0 = blockIdx.y * 256;                // 16 n-chunks
    int c0 = blockIdx.x * 256;                // 2 c-halves
    int wave = threadIdx.x >> 6, lane = threadIdx.x & 63;
    int cw = c0 + wave * 64;                  // wave owns 64 c-cols
    int l16 = lane & 15, g = lane >> 4;

    f32x4 acc[4][4] = {};                     // [mi][cj]
    const __hip_bfloat16* kp = Kb + (size_t)b * DD * NN;
    const float* xp = x + (size_t)b * CC * NN;

#pragma unroll
    for (int ks = 0; ks < 8; ++ks) {          // 256 n in steps of 32
        int nk = n0 + ks * 32 + g * 8;
        short8 af[4];
#pragma unroll
        for (int mi = 0; mi < 4; ++mi)
            af[mi] = *reinterpret_cast<const short8*>(kp + (size_t)(mi * 16 + l16) * NN + nk);
        short8 bf[4];
#pragma unroll
        for (int cj = 0; cj < 4; ++cj) {
            const float* xr = xp + (size_t)(cw + cj * 16 + l16) * NN + nk;
            f32x4 lo = *reinterpret_cast<const f32x4*>(xr);
            f32x4 hi = *reinterpret_cast<const f32x4*>(xr + 4);
            short8 v;
#pragma unroll
            for (int e = 0; e < 4; ++e) { v[e] = bf16s(lo[e]); v[4 + e] = bf16s(hi[e]); }
            bf[cj] = v;
        }
#pragma unroll
        for (int mi = 0; mi < 4; ++mi)
#pragma unroll
            for (int cj = 0; cj < 4; ++cj)
                acc[mi][cj] = __builtin_amdgcn_mfma_f32_16x16x32_bf16(af[mi], bf[cj], acc[mi][cj], 0, 0, 0);
    }
#pragma unroll
    for (int mi = 0; mi < 4; ++mi)
#pragma unroll
        for (int cj = 0; cj < 4; ++cj)
#pragma unroll
            for (int r = 0; r < 4; ++r) {
                int m = mi * 16 + 4 * g + r;
                int c = cw + cj * 16 + l16;
                atomicAdd(&KX[((size_t)(b * DD + m)) * CC + c], acc[mi][cj][r]);
            }
}

// ---- KVTb[b][c][m] = sum_cp KX[b][m][cp]*Wv[c][cp] + bv[c]*Ksum[b][m]
//      MFMA, no LDS, split hi/lo bf16 for ~fp32 accuracy. ----
__global__ __launch_bounds__(256) void k_kv(const float* __restrict__ KX,
                                            const float* __restrict__ Wv,
                                            const float* __restrict__ bv,
                                            const float* __restrict__ Ksum,
                                            __hip_bfloat16* __restrict__ KVTb) {
    int b = blockIdx.y;
    int c0 = blockIdx.x * 64;
    int wave = threadIdx.x >> 6, lane = threadIdx.x & 63;
    int cw = c0 + wave * 16;                  // wave owns 16 c-rows, all 64 m
    int l16 = lane & 15, g = lane >> 4;

    f32x4 acc[4] = {};                        // [mj]
    const float* wvp = Wv + (size_t)(cw + l16) * CC;
    const float* kxp = KX + (size_t)b * DD * CC;

#pragma unroll
    for (int ck = 0; ck < 16; ++ck) {         // 512 cp in steps of 32
        int cp = ck * 32 + g * 8;
        f32x4 w0 = *reinterpret_cast<const f32x4*>(wvp + cp);
        f32x4 w1 = *reinterpret_cast<const f32x4*>(wvp + cp + 4);
        short8 a_hi, a_lo;
#pragma unroll
        for (int e = 0; e < 4; ++e) {
            a_hi[e] = bf16s(w0[e]);     a_lo[e] = bf16s(w0[e] - sbf16(a_hi[e]));
            a_hi[4 + e] = bf16s(w1[e]); a_lo[4 + e] = bf16s(w1[e] - sbf16(a_hi[4 + e]));
        }
#pragma unroll
        for (int mj = 0; mj < 4; ++mj) {
            const float* kr = kxp + (size_t)(mj * 16 + l16) * CC + cp;
            f32x4 k0 = *reinterpret_cast<const f32x4*>(kr);
            f32x4 k1 = *reinterpret_cast<const f32x4*>(kr + 4);
            short8 b_hi, b_lo;
#pragma unroll
            for (int e = 0; e < 4; ++e) {
                b_hi[e] = bf16s(k0[e]);     b_lo[e] = bf16s(k0[e] - sbf16(b_hi[e]));
                b_hi[4 + e] = bf16s(k1[e]); b_lo[4 + e] = bf16s(k1[e] - sbf16(b_hi[4 + e]));
            }
            acc[mj] = __builtin_amdgcn_mfma_f32_16x16x32_bf16(a_hi, b_hi, acc[mj], 0, 0, 0);
            acc[mj] = __builtin_amdgcn_mfma_f32_16x16x32_bf16(a_lo, b_hi, acc[mj], 0, 0, 0);
            acc[mj] = __builtin_amdgcn_mfma_f32_16x16x32_bf16(a_hi, b_lo, acc[mj], 0, 0, 0);
        }
    }
#pragma unroll
    for (int mj = 0; mj < 4; ++mj)
#pragma unroll
        for (int r = 0; r < 4; ++r) {
            int c = cw + 4 * g + r;
            int m = mj * 16 + l16;
            KVTb[((size_t)b * CC + c) * DD + m] =
                __float2bfloat16(acc[mj][r] + bv[c] * Ksum[b * DD + m]);
        }
}

// ---- out[c][n] = x + (gamma/dot(Q[n],Ksum+eps)) * sum_m KVT[c][m]*Q[n][m]
//      MFMA K=64, norm fused in-register ----
__global__ __launch_bounds__(256) void k_out(const float* __restrict__ x,
                                             const __hip_bfloat16* __restrict__ Qb,
                                             const __hip_bfloat16* __restrict__ KVTb,
                                             const float* __restrict__ Ksum,
                                             const float* __restrict__ gamma,
                                             float* __restrict__ out) {
    int b = blockIdx.z;
    int c_blk = blockIdx.x * 128, n_blk = blockIdx.y * 128;
    int wave = threadIdx.x >> 6, lane = threadIdx.x & 63;
    int cw = c_blk + (wave >> 1) * 64, nw = n_blk + (wave & 1) * 64;
    int l16 = lane & 15, g = lane >> 4;

    float ksv[2][8];
#pragma unroll
    for (int ck = 0; ck < 2; ++ck)
#pragma unroll
        for (int e = 0; e < 8; ++e)
            ksv[ck][e] = Ksum[b * DD + (ck * 4 + g) * 8 + e] + EPSV;

    f32x4 acc[4][4] = {};
    float dot[4] = {0.f, 0.f, 0.f, 0.f};
    const short8* ap = reinterpret_cast<const short8*>(KVTb) + ((size_t)b * CC + cw) * 8;
    const short8* bp = reinterpret_cast<const short8*>(Qb) + ((size_t)b * NN + nw) * 8;
#pragma unroll
    for (int ck = 0; ck < 2; ++ck) {
        int ch = ck * 4 + g;
        short8 af[4], bf[4];
#pragma unroll
        for (int i = 0; i < 4; ++i) af[i] = ap[(size_t)(i * 16 + l16) * 8 + ch];
#pragma unroll
        for (int i = 0; i < 4; ++i) bf[i] = bp[(size_t)(i * 16 + l16) * 8 + ch];
#pragma unroll
        for (int j = 0; j < 4; ++j)
#pragma unroll
            for (int e = 0; e < 8; ++e)
                dot[j] = fmaf(sbf16(bf[j][e]), ksv[ck][e], dot[j]);
#pragma unroll
        for (int i = 0; i < 4; ++i)
#pragma unroll
            for (int j = 0; j < 4; ++j)
                acc[i][j] = __builtin_amdgcn_mfma_f32_16x16x32_bf16(af[i], bf[j], acc[i][j], 0, 0, 0);
    }
    float gm = gamma[0];
    float sc[4];
#pragma unroll
    for (int j = 0; j < 4; ++j) {
        float d = dot[j];
        d += __shfl_xor(d, 16, 64);
        d += __shfl_xor(d, 32, 64);
        sc[j] = gm / d;
    }
    const float* xb = x + (size_t)b * CC * NN;
    float* ob = out + (size_t)b * CC * NN;
#pragma unroll
    for (int i = 0; i < 4; ++i)
#pragma unroll
        for (int r = 0; r < 4; ++r) {
            int c = cw + i * 16 + 4 * g + r;
            size_t rowoff = (size_t)c * NN;
#pragma unroll
            for (int j = 0; j < 4; ++j) {
                int n = nw + j * 16 + l16;
                ob[rowoff + n] = xb[rowoff + n] + sc[j] * acc[i][j][r];
            }
        }
}

extern "C" void kernel_launch(void* const* d_in, const int* in_sizes, int n_in,
                              void* d_out, int out_size, void* d_ws, size_t ws_size,
                              hipStream_t stream) {
    const float* x     = (const float*)d_in[0];
    const float* Wq    = (const float*)d_in[1];
    const float* bq    = (const float*)d_in[2];
    const float* Wk    = (const float*)d_in[3];
    const float* bk    = (const float*)d_in[4];
    const float* Wv    = (const float*)d_in[5];
    const float* bv    = (const float*)d_in[6];
    const float* gamma = (const float*)d_in[7];
    float* out = (float*)d_out;

    float* ws    = (float*)d_ws;
    float* KX    = ws;                                   // B*D*C fp32 (2MB)
    float* Ksum  = KX + (size_t)BB * DD * CC;            // B*D fp32
    __hip_bfloat16* Qb   = (__hip_bfloat16*)(Ksum + BB * DD);  // B*N*D bf16
    __hip_bfloat16* Kb   = Qb + (size_t)BB * NN * DD;    // B*D*N bf16
    __hip_bfloat16* KVTb = Kb + (size_t)BB * DD * NN;    // B*C*D bf16
    __hip_bfloat16* Wcat = KVTb + (size_t)BB * CC * DD;  // 128*C bf16
    __hip_bfloat16* xt   = Wcat + 128 * CC;              // B*N*C bf16 (64MB)

    k_prep<<<dim3(769), dim3(256), 0, stream>>>(Wq, Wk, Wcat, KX, Ksum);
    k_xt<<<dim3(NN / 64, CC / 64, BB), dim3(256), 0, stream>>>(x, xt);
    k_proj<<<dim3(NN / 128, BB), dim3(256), 0, stream>>>(xt, Wcat, bq, bk, Qb, Kb, Ksum);
    k_kx<<<dim3(2, 16, BB), dim3(256), 0, stream>>>(Kb, x, KX);
    k_kv<<<dim3(CC / 64, BB), dim3(256), 0, stream>>>(KX, Wv, bv, Ksum, KVTb);
    k_out<<<dim3(CC / 128, NN / 128, BB), dim3(256), 0, stream>>>(x, Qb, KVTb, Ksum, gamma, out);
}

// Round 12
// 245.852 us; speedup vs baseline: 1.1400x; 1.0042x over previous
//
#include <hip/hip_runtime.h>
#include <hip/hip_bf16.h>
#include <math.h>

#define BB 16
#define CC 512
#define DD 64
#define NN 4096
#define EPSV 1e-6f

typedef __attribute__((ext_vector_type(8))) short short8;
typedef __attribute__((ext_vector_type(4))) float f32x4;

__device__ __forceinline__ float softplus_f(float v) {
    return fmaxf(v, 0.0f) + log1pf(expf(-fabsf(v)));
}
__device__ __forceinline__ short bf16s(float f) {
    __hip_bfloat16 h = __float2bfloat16(f);
    return __builtin_bit_cast(short, h);
}
__device__ __forceinline__ float sbf16(short s) {
    return __bfloat162float(__builtin_bit_cast(__hip_bfloat16, s));
}

// ---- prep: Wcat bf16 [128][512] (blocks 0-255), zero KX (256-767), zero Ksum (768) ----
__global__ __launch_bounds__(256) void k_prep(const float* __restrict__ Wq,
                                              const float* __restrict__ Wk,
                                              __hip_bfloat16* __restrict__ Wcat,
                                              float* __restrict__ KX,
                                              float* __restrict__ Ksum) {
    int blk = blockIdx.x;
    if (blk < 256) {
        int i = blk * 256 + threadIdx.x;
        int j = i >> 9, c = i & 511;
        float v = (j < DD) ? Wq[j * CC + c] : Wk[(j - DD) * CC + c];
        Wcat[i] = __float2bfloat16(v);
    } else if (blk < 768) {
        int i = (blk - 256) * 256 + threadIdx.x;   // 512*256 f32x4 = 2MB
        f32x4 z = {0.f, 0.f, 0.f, 0.f};
        reinterpret_cast<f32x4*>(KX)[i] = z;
    } else {
        f32x4 z = {0.f, 0.f, 0.f, 0.f};
        reinterpret_cast<f32x4*>(Ksum)[threadIdx.x] = z;  // 1024 floats
    }
}

// ---- prep: xt[b][n][c] bf16 (transpose of x) — pure streaming ----
__global__ __launch_bounds__(256) void k_xt(const float* __restrict__ x,
                                            __hip_bfloat16* __restrict__ xt) {
    int b = blockIdx.z;
    int n0 = blockIdx.x * 64, c0 = blockIdx.y * 64;
    __shared__ float tile[64][65];
    const float* xb = x + ((size_t)b * CC + c0) * NN + n0;
    int t = threadIdx.x;
#pragma unroll
    for (int i = 0; i < 16; ++i) {
        int idx = i * 256 + t;
        int c = idx >> 6, n = idx & 63;
        tile[c][n] = xb[(size_t)c * NN + n];
    }
    __syncthreads();
    __hip_bfloat16* xo = xt + ((size_t)b * NN + n0) * CC + c0;
#pragma unroll
    for (int i = 0; i < 16; ++i) {
        int idx = i * 256 + t;
        int n = idx >> 6, c = idx & 63;
        xo[(size_t)n * CC + c] = __float2bfloat16(tile[c][n]);
    }
}

// ---- Q/K projection via MFMA from xt, register double-buffered (no LDS, no barriers).
//      Fused Ksum. Qb[b][n][d] bf16 ; Kb[b][m][n] bf16 ----
__global__ __launch_bounds__(256, 2) void k_proj(const __hip_bfloat16* __restrict__ xt,
                                                 const __hip_bfloat16* __restrict__ Wcat,
                                                 const float* __restrict__ bq,
                                                 const float* __restrict__ bk,
                                                 __hip_bfloat16* __restrict__ Qb,
                                                 __hip_bfloat16* __restrict__ Kb,
                                                 float* __restrict__ Ksum) {
    int b = blockIdx.y;
    int n_blk = blockIdx.x * 128;
    int wave = threadIdx.x >> 6;
    int lane = threadIdx.x & 63;
    int n_wave = n_blk + wave * 32;           // wave owns 32 n-rows
    int l16 = lane & 15, g = lane >> 4;

    f32x4 accQ[2][4] = {};                    // D[n][j], j in [0,64)
    f32x4 accK[4][2] = {};                    // D[j][n], j in [64,128)

    const short8* xtp = reinterpret_cast<const short8*>(xt) + ((size_t)b * NN + n_wave) * 64;
    const short8* wp  = reinterpret_cast<const short8*>(Wcat);

    short8 xfA[2], wfA[8], xfB[2], wfB[8];

#define LOADX(dst, ck)                                                        \
    {                                                                         \
        _Pragma("unroll")                                                     \
        for (int nf = 0; nf < 2; ++nf)                                        \
            dst[nf] = xtp[(size_t)(nf * 16 + l16) * 64 + (ck) * 4 + g];       \
    }
#define LOADW(dst, ck)                                                        \
    {                                                                         \
        _Pragma("unroll")                                                     \
        for (int jf = 0; jf < 8; ++jf)                                        \
            dst[jf] = wp[(size_t)(jf * 16 + l16) * 64 + (ck) * 4 + g];        \
    }
#define DO_MFMA(xf, wf)                                                       \
    {                                                                         \
        _Pragma("unroll")                                                     \
        for (int nf = 0; nf < 2; ++nf)                                        \
            _Pragma("unroll")                                                 \
            for (int jf = 0; jf < 4; ++jf)                                    \
                accQ[nf][jf] = __builtin_amdgcn_mfma_f32_16x16x32_bf16(       \
                    xf[nf], wf[jf], accQ[nf][jf], 0, 0, 0);                   \
        _Pragma("unroll")                                                     \
        for (int jf = 0; jf < 4; ++jf)                                        \
            _Pragma("unroll")                                                 \
            for (int nf = 0; nf < 2; ++nf)                                    \
                accK[jf][nf] = __builtin_amdgcn_mfma_f32_16x16x32_bf16(       \
                    wf[4 + jf], xf[nf], accK[jf][nf], 0, 0, 0);               \
    }

    LOADX(xfA, 0); LOADW(wfA, 0);
    for (int ck2 = 0; ck2 < 8; ++ck2) {
        int ck = ck2 * 2;
        LOADX(xfB, ck + 1); LOADW(wfB, ck + 1);   // in flight during A-MFMAs
        DO_MFMA(xfA, wfA);
        if (ck2 < 7) { LOADX(xfA, ck + 2); LOADW(wfA, ck + 2); }  // in flight during B-MFMAs
        DO_MFMA(xfB, wfB);
    }
#undef LOADX
#undef LOADW
#undef DO_MFMA

    // Q epilogue: row n = n_wave + nf*16 + 4g + r, col j = jf*16 + l16
#pragma unroll
    for (int nf = 0; nf < 2; ++nf)
#pragma unroll
        for (int jf = 0; jf < 4; ++jf)
#pragma unroll
            for (int r = 0; r < 4; ++r) {
                int n = n_wave + nf * 16 + 4 * g + r;
                int j = jf * 16 + l16;
                float v = softplus_f(accQ[nf][jf][r] + bq[j]);
                Qb[((size_t)b * NN + n) * DD + j] = __float2bfloat16(v);
            }
    // K epilogue: row m = jf*16 + 4g + r, col n = n_wave + nf*16 + l16; fused Ksum
#pragma unroll
    for (int jf = 0; jf < 4; ++jf)
#pragma unroll
        for (int r = 0; r < 4; ++r) {
            int m = jf * 16 + 4 * g + r;
            float s = 0.f;
#pragma unroll
            for (int nf = 0; nf < 2; ++nf) {
                int n = n_wave + nf * 16 + l16;
                float v = softplus_f(accK[jf][nf][r] + bk[m]);
                Kb[((size_t)b * DD + m) * NN + n] = __float2bfloat16(v);
                s += v;
            }
            s += __shfl_xor(s, 1, 64);
            s += __shfl_xor(s, 2, 64);
            s += __shfl_xor(s, 4, 64);
            s += __shfl_xor(s, 8, 64);
            if (l16 == 0) atomicAdd(&Ksum[b * DD + m], s);
        }
}

// ---- KX[b][m][c] += sum_nn Kb[m][nn]*x[c][nn]  (MFMA, no LDS, split-K atomics) ----
__global__ __launch_bounds__(256) void k_kx(const __hip_bfloat16* __restrict__ Kb,
                                            const float* __restrict__ x,
                                            float* __restrict__ KX) {
    int b = blockIdx.z;
    int n0 = blockIdx.y * 256;                // 16 n-chunks
    int c0 = blockIdx.x * 256;                // 2 c-halves
    int wave = threadIdx.x >> 6, lane = threadIdx.x & 63;
    int cw = c0 + wave * 64;                  // wave owns 64 c-cols
    int l16 = lane & 15, g = lane >> 4;

    f32x4 acc[4][4] = {};                     // [mi][cj]
    const __hip_bfloat16* kp = Kb + (size_t)b * DD * NN;
    const float* xp = x + (size_t)b * CC * NN;

#pragma unroll
    for (int ks = 0; ks < 8; ++ks) {          // 256 n in steps of 32
        int nk = n0 + ks * 32 + g * 8;
        short8 af[4];
#pragma unroll
        for (int mi = 0; mi < 4; ++mi)
            af[mi] = *reinterpret_cast<const short8*>(kp + (size_t)(mi * 16 + l16) * NN + nk);
        short8 bf[4];
#pragma unroll
        for (int cj = 0; cj < 4; ++cj) {
            const float* xr = xp + (size_t)(cw + cj * 16 + l16) * NN + nk;
            f32x4 lo = *reinterpret_cast<const f32x4*>(xr);
            f32x4 hi = *reinterpret_cast<const f32x4*>(xr + 4);
            short8 v;
#pragma unroll
            for (int e = 0; e < 4; ++e) { v[e] = bf16s(lo[e]); v[4 + e] = bf16s(hi[e]); }
            bf[cj] = v;
        }
#pragma unroll
        for (int mi = 0; mi < 4; ++mi)
#pragma unroll
            for (int cj = 0; cj < 4; ++cj)
                acc[mi][cj] = __builtin_amdgcn_mfma_f32_16x16x32_bf16(af[mi], bf[cj], acc[mi][cj], 0, 0, 0);
    }
#pragma unroll
    for (int mi = 0; mi < 4; ++mi)
#pragma unroll
        for (int cj = 0; cj < 4; ++cj)
#pragma unroll
            for (int r = 0; r < 4; ++r) {
                int m = mi * 16 + 4 * g + r;
                int c = cw + cj * 16 + l16;
                atomicAdd(&KX[((size_t)(b * DD + m)) * CC + c], acc[mi][cj][r]);
            }
}

// ---- KVTb[b][c][m] = sum_cp KX[b][m][cp]*Wv[c][cp] + bv[c]*Ksum[b][m]
//      MFMA, no LDS, split hi/lo bf16 for ~fp32 accuracy. ----
__global__ __launch_bounds__(256) void k_kv(const float* __restrict__ KX,
                                            const float* __restrict__ Wv,
                                            const float* __restrict__ bv,
                                            const float* __restrict__ Ksum,
                                            __hip_bfloat16* __restrict__ KVTb) {
    int b = blockIdx.y;
    int c0 = blockIdx.x * 64;
    int wave = threadIdx.x >> 6, lane = threadIdx.x & 63;
    int cw = c0 + wave * 16;                  // wave owns 16 c-rows, all 64 m
    int l16 = lane & 15, g = lane >> 4;

    f32x4 acc[4] = {};                        // [mj]
    const float* wvp = Wv + (size_t)(cw + l16) * CC;
    const float* kxp = KX + (size_t)b * DD * CC;

#pragma unroll
    for (int ck = 0; ck < 16; ++ck) {         // 512 cp in steps of 32
        int cp = ck * 32 + g * 8;
        f32x4 w0 = *reinterpret_cast<const f32x4*>(wvp + cp);
        f32x4 w1 = *reinterpret_cast<const f32x4*>(wvp + cp + 4);
        short8 a_hi, a_lo;
#pragma unroll
        for (int e = 0; e < 4; ++e) {
            a_hi[e] = bf16s(w0[e]);     a_lo[e] = bf16s(w0[e] - sbf16(a_hi[e]));
            a_hi[4 + e] = bf16s(w1[e]); a_lo[4 + e] = bf16s(w1[e] - sbf16(a_hi[4 + e]));
        }
#pragma unroll
        for (int mj = 0; mj < 4; ++mj) {
            const float* kr = kxp + (size_t)(mj * 16 + l16) * CC + cp;
            f32x4 k0 = *reinterpret_cast<const f32x4*>(kr);
            f32x4 k1 = *reinterpret_cast<const f32x4*>(kr + 4);
            short8 b_hi, b_lo;
#pragma unroll
            for (int e = 0; e < 4; ++e) {
                b_hi[e] = bf16s(k0[e]);     b_lo[e] = bf16s(k0[e] - sbf16(b_hi[e]));
                b_hi[4 + e] = bf16s(k1[e]); b_lo[4 + e] = bf16s(k1[e] - sbf16(b_hi[4 + e]));
            }
            acc[mj] = __builtin_amdgcn_mfma_f32_16x16x32_bf16(a_hi, b_hi, acc[mj], 0, 0, 0);
            acc[mj] = __builtin_amdgcn_mfma_f32_16x16x32_bf16(a_lo, b_hi, acc[mj], 0, 0, 0);
            acc[mj] = __builtin_amdgcn_mfma_f32_16x16x32_bf16(a_hi, b_lo, acc[mj], 0, 0, 0);
        }
    }
#pragma unroll
    for (int mj = 0; mj < 4; ++mj)
#pragma unroll
        for (int r = 0; r < 4; ++r) {
            int c = cw + 4 * g + r;
            int m = mj * 16 + l16;
            KVTb[((size_t)b * CC + c) * DD + m] =
                __float2bfloat16(acc[mj][r] + bv[c] * Ksum[b * DD + m]);
        }
}

// ---- out[c][n] = x + (gamma/dot(Q[n],Ksum+eps)) * sum_m KVT[c][m]*Q[n][m]
//      MFMA K=64, norm fused in-register ----
__global__ __launch_bounds__(256) void k_out(const float* __restrict__ x,
                                             const __hip_bfloat16* __restrict__ Qb,
                                             const __hip_bfloat16* __restrict__ KVTb,
                                             const float* __restrict__ Ksum,
                                             const float* __restrict__ gamma,
                                             float* __restrict__ out) {
    int b = blockIdx.z;
    int c_blk = blockIdx.x * 128, n_blk = blockIdx.y * 128;
    int wave = threadIdx.x >> 6, lane = threadIdx.x & 63;
    int cw = c_blk + (wave >> 1) * 64, nw = n_blk + (wave & 1) * 64;
    int l16 = lane & 15, g = lane >> 4;

    float ksv[2][8];
#pragma unroll
    for (int ck = 0; ck < 2; ++ck)
#pragma unroll
        for (int e = 0; e < 8; ++e)
            ksv[ck][e] = Ksum[b * DD + (ck * 4 + g) * 8 + e] + EPSV;

    f32x4 acc[4][4] = {};
    float dot[4] = {0.f, 0.f, 0.f, 0.f};
    const short8* ap = reinterpret_cast<const short8*>(KVTb) + ((size_t)b * CC + cw) * 8;
    const short8* bp = reinterpret_cast<const short8*>(Qb) + ((size_t)b * NN + nw) * 8;
#pragma unroll
    for (int ck = 0; ck < 2; ++ck) {
        int ch = ck * 4 + g;
        short8 af[4], bf[4];
#pragma unroll
        for (int i = 0; i < 4; ++i) af[i] = ap[(size_t)(i * 16 + l16) * 8 + ch];
#pragma unroll
        for (int i = 0; i < 4; ++i) bf[i] = bp[(size_t)(i * 16 + l16) * 8 + ch];
#pragma unroll
        for (int j = 0; j < 4; ++j)
#pragma unroll
            for (int e = 0; e < 8; ++e)
                dot[j] = fmaf(sbf16(bf[j][e]), ksv[ck][e], dot[j]);
#pragma unroll
        for (int i = 0; i < 4; ++i)
#pragma unroll
            for (int j = 0; j < 4; ++j)
                acc[i][j] = __builtin_amdgcn_mfma_f32_16x16x32_bf16(af[i], bf[j], acc[i][j], 0, 0, 0);
    }
    float gm = gamma[0];
    float sc[4];
#pragma unroll
    for (int j = 0; j < 4; ++j) {
        float d = dot[j];
        d += __shfl_xor(d, 16, 64);
        d += __shfl_xor(d, 32, 64);
        sc[j] = gm / d;
    }
    const float* xb = x + (size_t)b * CC * NN;
    float* ob = out + (size_t)b * CC * NN;
#pragma unroll
    for (int i = 0; i < 4; ++i)
#pragma unroll
        for (int r = 0; r < 4; ++r) {
            int c = cw + i * 16 + 4 * g + r;
            size_t rowoff = (size_t)c * NN;
#pragma unroll
            for (int j = 0; j < 4; ++j) {
                int n = nw + j * 16 + l16;
                ob[rowoff + n] = xb[rowoff + n] + sc[j] * acc[i][j][r];
            }
        }
}

extern "C" void kernel_launch(void* const* d_in, const int* in_sizes, int n_in,
                              void* d_out, int out_size, void* d_ws, size_t ws_size,
                              hipStream_t stream) {
    const float* x     = (const float*)d_in[0];
    const float* Wq    = (const float*)d_in[1];
    const float* bq    = (const float*)d_in[2];
    const float* Wk    = (const float*)d_in[3];
    const float* bk    = (const float*)d_in[4];
    const float* Wv    = (const float*)d_in[5];
    const float* bv    = (const float*)d_in[6];
    const float* gamma = (const float*)d_in[7];
    float* out = (float*)d_out;

    float* ws    = (float*)d_ws;
    float* KX    = ws;                                   // B*D*C fp32 (2MB)
    float* Ksum  = KX + (size_t)BB * DD * CC;            // B*D fp32
    __hip_bfloat16* Qb   = (__hip_bfloat16*)(Ksum + BB * DD);  // B*N*D bf16
    __hip_bfloat16* Kb   = Qb + (size_t)BB * NN * DD;    // B*D*N bf16
    __hip_bfloat16* KVTb = Kb + (size_t)BB * DD * NN;    // B*C*D bf16
    __hip_bfloat16* Wcat = KVTb + (size_t)BB * CC * DD;  // 128*C bf16
    __hip_bfloat16* xt   = Wcat + 128 * CC;              // B*N*C bf16 (64MB)

    k_prep<<<dim3(769), dim3(256), 0, stream>>>(Wq, Wk, Wcat, KX, Ksum);
    k_xt<<<dim3(NN / 64, CC / 64, BB), dim3(256), 0, stream>>>(x, xt);
    k_proj<<<dim3(NN / 128, BB), dim3(256), 0, stream>>>(xt, Wcat, bq, bk, Qb, Kb, Ksum);
    k_kx<<<dim3(2, 16, BB), dim3(256), 0, stream>>>(Kb, x, KX);
    k_kv<<<dim3(CC / 64, BB), dim3(256), 0, stream>>>(KX, Wv, bv, Ksum, KVTb);
    k_out<<<dim3(CC / 128, NN / 128, BB), dim3(256), 0, stream>>>(x, Qb, KVTb, Ksum, gamma, out);
}

// Round 13
// 235.738 us; speedup vs baseline: 1.1889x; 1.0429x over previous
//
#include <hip/hip_runtime.h>
#include <hip/hip_bf16.h>
#include <math.h>

#define BB 16
#define CC 512
#define DD 64
#define NN 4096
#define EPSV 1e-6f

typedef __attribute__((ext_vector_type(8))) short short8;
typedef __attribute__((ext_vector_type(4))) float f32x4;

__device__ __forceinline__ float softplus_f(float v) {
    return fmaxf(v, 0.0f) + log1pf(expf(-fabsf(v)));
}
__device__ __forceinline__ short bf16s(float f) {
    __hip_bfloat16 h = __float2bfloat16(f);
    return __builtin_bit_cast(short, h);
}
__device__ __forceinline__ float sbf16(short s) {
    return __bfloat162float(__builtin_bit_cast(__hip_bfloat16, s));
}

// ---- prep: Wcat bf16 [128][512] (blocks 0-255), zero KX (256-767), zero Ksum (768) ----
__global__ __launch_bounds__(256) void k_prep(const float* __restrict__ Wq,
                                              const float* __restrict__ Wk,
                                              __hip_bfloat16* __restrict__ Wcat,
                                              float* __restrict__ KX,
                                              float* __restrict__ Ksum) {
    int blk = blockIdx.x;
    if (blk < 256) {
        int i = blk * 256 + threadIdx.x;
        int j = i >> 9, c = i & 511;
        float v = (j < DD) ? Wq[j * CC + c] : Wk[(j - DD) * CC + c];
        Wcat[i] = __float2bfloat16(v);
    } else if (blk < 768) {
        int i = (blk - 256) * 256 + threadIdx.x;   // 512*256 f32x4 = 2MB
        f32x4 z = {0.f, 0.f, 0.f, 0.f};
        reinterpret_cast<f32x4*>(KX)[i] = z;
    } else {
        f32x4 z = {0.f, 0.f, 0.f, 0.f};
        reinterpret_cast<f32x4*>(Ksum)[threadIdx.x] = z;  // 1024 floats
    }
}

// ---- prep: xt[b][n][c] bf16 (transpose of x) — pure streaming ----
__global__ __launch_bounds__(256) void k_xt(const float* __restrict__ x,
                                            __hip_bfloat16* __restrict__ xt) {
    int b = blockIdx.z;
    int n0 = blockIdx.x * 64, c0 = blockIdx.y * 64;
    __shared__ float tile[64][65];
    const float* xb = x + ((size_t)b * CC + c0) * NN + n0;
    int t = threadIdx.x;
#pragma unroll
    for (int i = 0; i < 16; ++i) {
        int idx = i * 256 + t;
        int c = idx >> 6, n = idx & 63;
        tile[c][n] = xb[(size_t)c * NN + n];
    }
    __syncthreads();
    __hip_bfloat16* xo = xt + ((size_t)b * NN + n0) * CC + c0;
#pragma unroll
    for (int i = 0; i < 16; ++i) {
        int idx = i * 256 + t;
        int n = idx >> 6, c = idx & 63;
        xo[(size_t)n * CC + c] = __float2bfloat16(tile[c][n]);
    }
}

// ---- Q/K projection. blockIdx.z: 0 = Q-half, 1 = K-half.
//      W-half (64x512 bf16, 64KB) staged in LDS ONCE (XOR-swizzled chunks),
//      then barrier-free main loop: 2 xt global reads + 4 ds_read_b128 + 8 MFMA per ck.
//      Fused Ksum (K-type blocks). Qb[b][n][d] bf16 ; Kb[b][m][n] bf16 ----
__global__ __launch_bounds__(256, 2) void k_proj(const __hip_bfloat16* __restrict__ xt,
                                                 const __hip_bfloat16* __restrict__ Wcat,
                                                 const float* __restrict__ bq,
                                                 const float* __restrict__ bk,
                                                 __hip_bfloat16* __restrict__ Qb,
                                                 __hip_bfloat16* __restrict__ Kb,
                                                 float* __restrict__ Ksum) {
    extern __shared__ short wlds[];            // [64][512] bf16, chunk-swizzled rows

    int typ = blockIdx.z;                      // 0 = Q, 1 = K
    int b = blockIdx.y;
    int n_blk = blockIdx.x * 128;
    int t = threadIdx.x;
    int wave = t >> 6, lane = t & 63;
    int n_wave = n_blk + wave * 32;            // wave owns 32 n-rows
    int l16 = lane & 15, g = lane >> 4;

    // ---- stage W-half into LDS once. chunk (16B) index swizzle: ch' = ch ^ (row&7) ----
    {
        int row = t >> 2;                      // 0..63
        int cb = (t & 3) * 16;                 // base chunk (of 64 per row)
        const short8* wg = reinterpret_cast<const short8*>(Wcat) + (size_t)(typ * 64 + row) * 64;
        short8* wr = reinterpret_cast<short8*>(wlds + row * 512);
        int sw = row & 7;
#pragma unroll
        for (int k = 0; k < 16; ++k) {
            int ch = cb + k;
            wr[ch ^ sw] = wg[ch];
        }
    }
    __syncthreads();                           // only barrier in the kernel

    f32x4 acc[8] = {};                         // Q: acc[nf*4+jf] ; K: acc[jf*2+nf]
    const short8* xtp = reinterpret_cast<const short8*>(xt) + ((size_t)b * NN + n_wave) * 64;

#pragma unroll 4
    for (int ck = 0; ck < 16; ++ck) {
        int ch = ck * 4 + g;
        short8 xf[2], wf[4];
#pragma unroll
        for (int nf = 0; nf < 2; ++nf)
            xf[nf] = xtp[(size_t)(nf * 16 + l16) * 64 + ch];
#pragma unroll
        for (int jf = 0; jf < 4; ++jf) {
            int row = jf * 16 + l16;
            wf[jf] = *reinterpret_cast<const short8*>(wlds + row * 512 + (ch ^ (row & 7)) * 8);
        }
        if (typ == 0) {
#pragma unroll
            for (int nf = 0; nf < 2; ++nf)
#pragma unroll
                for (int jf = 0; jf < 4; ++jf)
                    acc[nf * 4 + jf] = __builtin_amdgcn_mfma_f32_16x16x32_bf16(
                        xf[nf], wf[jf], acc[nf * 4 + jf], 0, 0, 0);
        } else {
#pragma unroll
            for (int jf = 0; jf < 4; ++jf)
#pragma unroll
                for (int nf = 0; nf < 2; ++nf)
                    acc[jf * 2 + nf] = __builtin_amdgcn_mfma_f32_16x16x32_bf16(
                        wf[jf], xf[nf], acc[jf * 2 + nf], 0, 0, 0);
        }
    }

    if (typ == 0) {
        // Q epilogue: row n = n_wave + nf*16 + 4g + r, col j = jf*16 + l16
#pragma unroll
        for (int nf = 0; nf < 2; ++nf)
#pragma unroll
            for (int jf = 0; jf < 4; ++jf)
#pragma unroll
                for (int r = 0; r < 4; ++r) {
                    int n = n_wave + nf * 16 + 4 * g + r;
                    int j = jf * 16 + l16;
                    float v = softplus_f(acc[nf * 4 + jf][r] + bq[j]);
                    Qb[((size_t)b * NN + n) * DD + j] = __float2bfloat16(v);
                }
    } else {
        // K epilogue: row m = jf*16 + 4g + r, col n = n_wave + nf*16 + l16; fused Ksum
#pragma unroll
        for (int jf = 0; jf < 4; ++jf)
#pragma unroll
            for (int r = 0; r < 4; ++r) {
                int m = jf * 16 + 4 * g + r;
                float s = 0.f;
#pragma unroll
                for (int nf = 0; nf < 2; ++nf) {
                    int n = n_wave + nf * 16 + l16;
                    float v = softplus_f(acc[jf * 2 + nf][r] + bk[m]);
                    Kb[((size_t)b * DD + m) * NN + n] = __float2bfloat16(v);
                    s += v;
                }
                s += __shfl_xor(s, 1, 64);
                s += __shfl_xor(s, 2, 64);
                s += __shfl_xor(s, 4, 64);
                s += __shfl_xor(s, 8, 64);
                if (l16 == 0) atomicAdd(&Ksum[b * DD + m], s);
            }
    }
}

// ---- KX[b][m][c] += sum_nn Kb[m][nn]*x[c][nn]  (MFMA, no LDS, split-K atomics) ----
__global__ __launch_bounds__(256) void k_kx(const __hip_bfloat16* __restrict__ Kb,
                                            const float* __restrict__ x,
                                            float* __restrict__ KX) {
    int b = blockIdx.z;
    int n0 = blockIdx.y * 256;                // 16 n-chunks
    int c0 = blockIdx.x * 256;                // 2 c-halves
    int wave = threadIdx.x >> 6, lane = threadIdx.x & 63;
    int cw = c0 + wave * 64;                  // wave owns 64 c-cols
    int l16 = lane & 15, g = lane >> 4;

    f32x4 acc[4][4] = {};                     // [mi][cj]
    const __hip_bfloat16* kp = Kb + (size_t)b * DD * NN;
    const float* xp = x + (size_t)b * CC * NN;

#pragma unroll
    for (int ks = 0; ks < 8; ++ks) {          // 256 n in steps of 32
        int nk = n0 + ks * 32 + g * 8;
        short8 af[4];
#pragma unroll
        for (int mi = 0; mi < 4; ++mi)
            af[mi] = *reinterpret_cast<const short8*>(kp + (size_t)(mi * 16 + l16) * NN + nk);
        short8 bf[4];
#pragma unroll
        for (int cj = 0; cj < 4; ++cj) {
            const float* xr = xp + (size_t)(cw + cj * 16 + l16) * NN + nk;
            f32x4 lo = *reinterpret_cast<const f32x4*>(xr);
            f32x4 hi = *reinterpret_cast<const f32x4*>(xr + 4);
            short8 v;
#pragma unroll
            for (int e = 0; e < 4; ++e) { v[e] = bf16s(lo[e]); v[4 + e] = bf16s(hi[e]); }
            bf[cj] = v;
        }
#pragma unroll
        for (int mi = 0; mi < 4; ++mi)
#pragma unroll
            for (int cj = 0; cj < 4; ++cj)
                acc[mi][cj] = __builtin_amdgcn_mfma_f32_16x16x32_bf16(af[mi], bf[cj], acc[mi][cj], 0, 0, 0);
    }
#pragma unroll
    for (int mi = 0; mi < 4; ++mi)
#pragma unroll
        for (int cj = 0; cj < 4; ++cj)
#pragma unroll
            for (int r = 0; r < 4; ++r) {
                int m = mi * 16 + 4 * g + r;
                int c = cw + cj * 16 + l16;
                atomicAdd(&KX[((size_t)(b * DD + m)) * CC + c], acc[mi][cj][r]);
            }
}

// ---- KVTb[b][c][m] = sum_cp KX[b][m][cp]*Wv[c][cp] + bv[c]*Ksum[b][m]
//      MFMA, no LDS, split hi/lo bf16 for ~fp32 accuracy. ----
__global__ __launch_bounds__(256) void k_kv(const float* __restrict__ KX,
                                            const float* __restrict__ Wv,
                                            const float* __restrict__ bv,
                                            const float* __restrict__ Ksum,
                                            __hip_bfloat16* __restrict__ KVTb) {
    int b = blockIdx.y;
    int c0 = blockIdx.x * 64;
    int wave = threadIdx.x >> 6, lane = threadIdx.x & 63;
    int cw = c0 + wave * 16;                  // wave owns 16 c-rows, all 64 m
    int l16 = lane & 15, g = lane >> 4;

    f32x4 acc[4] = {};                        // [mj]
    const float* wvp = Wv + (size_t)(cw + l16) * CC;
    const float* kxp = KX + (size_t)b * DD * CC;

#pragma unroll
    for (int ck = 0; ck < 16; ++ck) {         // 512 cp in steps of 32
        int cp = ck * 32 + g * 8;
        f32x4 w0 = *reinterpret_cast<const f32x4*>(wvp + cp);
        f32x4 w1 = *reinterpret_cast<const f32x4*>(wvp + cp + 4);
        short8 a_hi, a_lo;
#pragma unroll
        for (int e = 0; e < 4; ++e) {
            a_hi[e] = bf16s(w0[e]);     a_lo[e] = bf16s(w0[e] - sbf16(a_hi[e]));
            a_hi[4 + e] = bf16s(w1[e]); a_lo[4 + e] = bf16s(w1[e] - sbf16(a_hi[4 + e]));
        }
#pragma unroll
        for (int mj = 0; mj < 4; ++mj) {
            const float* kr = kxp + (size_t)(mj * 16 + l16) * CC + cp;
            f32x4 k0 = *reinterpret_cast<const f32x4*>(kr);
            f32x4 k1 = *reinterpret_cast<const f32x4*>(kr + 4);
            short8 b_hi, b_lo;
#pragma unroll
            for (int e = 0; e < 4; ++e) {
                b_hi[e] = bf16s(k0[e]);     b_lo[e] = bf16s(k0[e] - sbf16(b_hi[e]));
                b_hi[4 + e] = bf16s(k1[e]); b_lo[4 + e] = bf16s(k1[e] - sbf16(b_hi[4 + e]));
            }
            acc[mj] = __builtin_amdgcn_mfma_f32_16x16x32_bf16(a_hi, b_hi, acc[mj], 0, 0, 0);
            acc[mj] = __builtin_amdgcn_mfma_f32_16x16x32_bf16(a_lo, b_hi, acc[mj], 0, 0, 0);
            acc[mj] = __builtin_amdgcn_mfma_f32_16x16x32_bf16(a_hi, b_lo, acc[mj], 0, 0, 0);
        }
    }
#pragma unroll
    for (int mj = 0; mj < 4; ++mj)
#pragma unroll
        for (int r = 0; r < 4; ++r) {
            int c = cw + 4 * g + r;
            int m = mj * 16 + l16;
            KVTb[((size_t)b * CC + c) * DD + m] =
                __float2bfloat16(acc[mj][r] + bv[c] * Ksum[b * DD + m]);
        }
}

// ---- out[c][n] = x + (gamma/dot(Q[n],Ksum+eps)) * sum_m KVT[c][m]*Q[n][m]
//      MFMA K=64, norm fused in-register ----
__global__ __launch_bounds__(256) void k_out(const float* __restrict__ x,
                                             const __hip_bfloat16* __restrict__ Qb,
                                             const __hip_bfloat16* __restrict__ KVTb,
                                             const float* __restrict__ Ksum,
                                             const float* __restrict__ gamma,
                                             float* __restrict__ out) {
    int b = blockIdx.z;
    int c_blk = blockIdx.x * 128, n_blk = blockIdx.y * 128;
    int wave = threadIdx.x >> 6, lane = threadIdx.x & 63;
    int cw = c_blk + (wave >> 1) * 64, nw = n_blk + (wave & 1) * 64;
    int l16 = lane & 15, g = lane >> 4;

    float ksv[2][8];
#pragma unroll
    for (int ck = 0; ck < 2; ++ck)
#pragma unroll
        for (int e = 0; e < 8; ++e)
            ksv[ck][e] = Ksum[b * DD + (ck * 4 + g) * 8 + e] + EPSV;

    f32x4 acc[4][4] = {};
    float dot[4] = {0.f, 0.f, 0.f, 0.f};
    const short8* ap = reinterpret_cast<const short8*>(KVTb) + ((size_t)b * CC + cw) * 8;
    const short8* bp = reinterpret_cast<const short8*>(Qb) + ((size_t)b * NN + nw) * 8;
#pragma unroll
    for (int ck = 0; ck < 2; ++ck) {
        int ch = ck * 4 + g;
        short8 af[4], bf[4];
#pragma unroll
        for (int i = 0; i < 4; ++i) af[i] = ap[(size_t)(i * 16 + l16) * 8 + ch];
#pragma unroll
        for (int i = 0; i < 4; ++i) bf[i] = bp[(size_t)(i * 16 + l16) * 8 + ch];
#pragma unroll
        for (int j = 0; j < 4; ++j)
#pragma unroll
            for (int e = 0; e < 8; ++e)
                dot[j] = fmaf(sbf16(bf[j][e]), ksv[ck][e], dot[j]);
#pragma unroll
        for (int i = 0; i < 4; ++i)
#pragma unroll
            for (int j = 0; j < 4; ++j)
                acc[i][j] = __builtin_amdgcn_mfma_f32_16x16x32_bf16(af[i], bf[j], acc[i][j], 0, 0, 0);
    }
    float gm = gamma[0];
    float sc[4];
#pragma unroll
    for (int j = 0; j < 4; ++j) {
        float d = dot[j];
        d += __shfl_xor(d, 16, 64);
        d += __shfl_xor(d, 32, 64);
        sc[j] = gm / d;
    }
    const float* xb = x + (size_t)b * CC * NN;
    float* ob = out + (size_t)b * CC * NN;
#pragma unroll
    for (int i = 0; i < 4; ++i)
#pragma unroll
        for (int r = 0; r < 4; ++r) {
            int c = cw + i * 16 + 4 * g + r;
            size_t rowoff = (size_t)c * NN;
#pragma unroll
            for (int j = 0; j < 4; ++j) {
                int n = nw + j * 16 + l16;
                ob[rowoff + n] = xb[rowoff + n] + sc[j] * acc[i][j][r];
            }
        }
}

extern "C" void kernel_launch(void* const* d_in, const int* in_sizes, int n_in,
                              void* d_out, int out_size, void* d_ws, size_t ws_size,
                              hipStream_t stream) {
    const float* x     = (const float*)d_in[0];
    const float* Wq    = (const float*)d_in[1];
    const float* bq    = (const float*)d_in[2];
    const float* Wk    = (const float*)d_in[3];
    const float* bk    = (const float*)d_in[4];
    const float* Wv    = (const float*)d_in[5];
    const float* bv    = (const float*)d_in[6];
    const float* gamma = (const float*)d_in[7];
    float* out = (float*)d_out;

    float* ws    = (float*)d_ws;
    float* KX    = ws;                                   // B*D*C fp32 (2MB)
    float* Ksum  = KX + (size_t)BB * DD * CC;            // B*D fp32
    __hip_bfloat16* Qb   = (__hip_bfloat16*)(Ksum + BB * DD);  // B*N*D bf16
    __hip_bfloat16* Kb   = Qb + (size_t)BB * NN * DD;    // B*D*N bf16
    __hip_bfloat16* KVTb = Kb + (size_t)BB * DD * NN;    // B*C*D bf16
    __hip_bfloat16* Wcat = KVTb + (size_t)BB * CC * DD;  // 128*C bf16
    __hip_bfloat16* xt   = Wcat + 128 * CC;              // B*N*C bf16 (64MB)

    k_prep<<<dim3(769), dim3(256), 0, stream>>>(Wq, Wk, Wcat, KX, Ksum);
    k_xt<<<dim3(NN / 64, CC / 64, BB), dim3(256), 0, stream>>>(x, xt);
    k_proj<<<dim3(NN / 128, BB, 2), dim3(256), 65536, stream>>>(xt, Wcat, bq, bk, Qb, Kb, Ksum);
    k_kx<<<dim3(2, 16, BB), dim3(256), 0, stream>>>(Kb, x, KX);
    k_kv<<<dim3(CC / 64, BB), dim3(256), 0, stream>>>(KX, Wv, bv, Ksum, KVTb);
    k_out<<<dim3(CC / 128, NN / 128, BB), dim3(256), 0, stream>>>(x, Qb, KVTb, Ksum, gamma, out);
}

// Round 14
// 218.587 us; speedup vs baseline: 1.2822x; 1.0785x over previous
//
#include <hip/hip_runtime.h>
#include <hip/hip_bf16.h>
#include <math.h>

#define BB 16
#define CC 512
#define DD 64
#define NN 4096
#define EPSV 1e-6f

typedef __attribute__((ext_vector_type(8))) short short8;
typedef __attribute__((ext_vector_type(4))) short s16x4;
typedef __attribute__((ext_vector_type(4))) float f32x4;

__device__ __forceinline__ float softplus_f(float v) {
    return fmaxf(v, 0.0f) + log1pf(expf(-fabsf(v)));
}
__device__ __forceinline__ short bf16s(float f) {
    __hip_bfloat16 h = __float2bfloat16(f);
    return __builtin_bit_cast(short, h);
}
__device__ __forceinline__ float sbf16(short s) {
    return __bfloat162float(__builtin_bit_cast(__hip_bfloat16, s));
}

// ---- prep: Wcat bf16 [128][512] (blocks 0-255), zero KX (256-767), zero Ksum (768) ----
__global__ __launch_bounds__(256) void k_prep(const float* __restrict__ Wq,
                                              const float* __restrict__ Wk,
                                              __hip_bfloat16* __restrict__ Wcat,
                                              float* __restrict__ KX,
                                              float* __restrict__ Ksum) {
    int blk = blockIdx.x;
    if (blk < 256) {
        int i = blk * 256 + threadIdx.x;
        int j = i >> 9, c = i & 511;
        float v = (j < DD) ? Wq[j * CC + c] : Wk[(j - DD) * CC + c];
        Wcat[i] = __float2bfloat16(v);
    } else if (blk < 768) {
        int i = (blk - 256) * 256 + threadIdx.x;   // 512*256 f32x4 = 2MB
        f32x4 z = {0.f, 0.f, 0.f, 0.f};
        reinterpret_cast<f32x4*>(KX)[i] = z;
    } else {
        f32x4 z = {0.f, 0.f, 0.f, 0.f};
        reinterpret_cast<f32x4*>(Ksum)[threadIdx.x] = z;  // 1024 floats
    }
}

// ---- Q/K projection via MFMA, x staged through LDS (fused transpose, double-buffered).
//      VERIFIED-BEST structure (round-6 kernel, 198us total, proj ~85-90).
//      Also accumulates Ksum[b][m]. Qb[b][n][d] bf16 ; Kb[b][m][n] bf16 ----
__global__ __launch_bounds__(256) void k_proj(const float* __restrict__ x,
                                              const __hip_bfloat16* __restrict__ Wcat,
                                              const float* __restrict__ bq,
                                              const float* __restrict__ bk,
                                              __hip_bfloat16* __restrict__ Qb,
                                              __hip_bfloat16* __restrict__ Kb,
                                              float* __restrict__ Ksum) {
    // xs: 32-c chunk of x, bf16, [c][n] rows padded to 132 u16 (264 B)
    // ws: 32-c chunk of Wcat, bf16, [j][c] rows padded to 40 u16 (80 B)
    __shared__ unsigned short xs[2][32][132];
    __shared__ unsigned short ws[2][128][40];

    int b = blockIdx.y;
    int n_blk = blockIdx.x * 128;
    int t = threadIdx.x;
    int wave = t >> 6, lane = t & 63;
    int nwl = wave * 32;                    // wave's local n base
    int n_wave = n_blk + nwl;
    int l16 = lane & 15, g = lane >> 4;

    // staging assignments
    int sv = t & 31;                        // x: 4-float group along n
    int sc = t >> 5;                        // x: base c-row (0..7), rows sc+8i
    int wj = t >> 1;                        // W: row j (0..127)
    int wh = t & 1;                         // W: 16-elem half of the 32-c chunk

    const float* xb = x + (size_t)b * CC * NN + n_blk + sv * 4;
    const unsigned short* wg = reinterpret_cast<const unsigned short*>(Wcat)
                               + (size_t)wj * 512 + wh * 16;

    f32x4 xr[4];
    s16x4 wr[4];

    auto loadx = [&](int c0) {
#pragma unroll
        for (int i = 0; i < 4; ++i)
            xr[i] = *reinterpret_cast<const f32x4*>(xb + (size_t)(c0 + sc + i * 8) * NN);
    };
    auto loadw = [&](int c0) {
#pragma unroll
        for (int k = 0; k < 4; ++k)
            wr[k] = *reinterpret_cast<const s16x4*>(wg + c0 + k * 4);
    };
    auto writex = [&](int bi) {
#pragma unroll
        for (int i = 0; i < 4; ++i) {
            s16x4 pv;
#pragma unroll
            for (int j = 0; j < 4; ++j) pv[j] = bf16s(xr[i][j]);
            *reinterpret_cast<s16x4*>(&xs[bi][sc + i * 8][sv * 4]) = pv;
        }
    };
    auto writew = [&](int bi) {
#pragma unroll
        for (int k = 0; k < 4; ++k)
            *reinterpret_cast<s16x4*>(&ws[bi][wj][wh * 16 + k * 4]) = wr[k];
    };

    f32x4 accQ[2][4] = {};                  // Q: D[n][j]
    f32x4 accK[4][2] = {};                  // K: D[j][n]

    loadx(0); loadw(0);
    writex(0); writew(0);

    for (int ck = 0; ck < 16; ++ck) {
        int cur = ck & 1;
        if (ck < 15) { loadx((ck + 1) * 32); loadw((ck + 1) * 32); }  // issue early (T14)
        __syncthreads();                     // buf[cur] ready; prev reads of buf[cur^1] done
        short8 xf[2], wf[8];
#pragma unroll
        for (int nf = 0; nf < 2; ++nf) {
            short8 v;
#pragma unroll
            for (int e = 0; e < 8; ++e)
                v[e] = (short)xs[cur][g * 8 + e][nwl + nf * 16 + l16];
            xf[nf] = v;
        }
#pragma unroll
        for (int jf = 0; jf < 8; ++jf)
            wf[jf] = *reinterpret_cast<const short8*>(&ws[cur][jf * 16 + l16][g * 8]);
#pragma unroll
        for (int nf = 0; nf < 2; ++nf)
#pragma unroll
            for (int jf = 0; jf < 4; ++jf)
                accQ[nf][jf] = __builtin_amdgcn_mfma_f32_16x16x32_bf16(xf[nf], wf[jf], accQ[nf][jf], 0, 0, 0);
#pragma unroll
        for (int jf = 0; jf < 4; ++jf)
#pragma unroll
            for (int nf = 0; nf < 2; ++nf)
                accK[jf][nf] = __builtin_amdgcn_mfma_f32_16x16x32_bf16(wf[4 + jf], xf[nf], accK[jf][nf], 0, 0, 0);
        if (ck < 15) { writex(cur ^ 1); writew(cur ^ 1); }   // other buffer: no race with cur readers
    }

    // Q epilogue: row n = n_wave + nf*16 + 4g + r, col j = jf*16 + l16
#pragma unroll
    for (int nf = 0; nf < 2; ++nf)
#pragma unroll
        for (int jf = 0; jf < 4; ++jf)
#pragma unroll
            for (int r = 0; r < 4; ++r) {
                int n = n_wave + nf * 16 + 4 * g + r;
                int j = jf * 16 + l16;
                float v = softplus_f(accQ[nf][jf][r] + bq[j]);
                Qb[((size_t)b * NN + n) * DD + j] = __float2bfloat16(v);
            }
    // K epilogue: row m = jf*16 + 4g + r, col n = n_wave + nf*16 + l16; fused Ksum
#pragma unroll
    for (int jf = 0; jf < 4; ++jf)
#pragma unroll
        for (int r = 0; r < 4; ++r) {
            int m = jf * 16 + 4 * g + r;
            float s = 0.f;
#pragma unroll
            for (int nf = 0; nf < 2; ++nf) {
                int n = n_wave + nf * 16 + l16;
                float v = softplus_f(accK[jf][nf][r] + bk[m]);
                Kb[((size_t)b * DD + m) * NN + n] = __float2bfloat16(v);
                s += v;
            }
            s += __shfl_xor(s, 1, 64);
            s += __shfl_xor(s, 2, 64);
            s += __shfl_xor(s, 4, 64);
            s += __shfl_xor(s, 8, 64);
            if (l16 == 0) atomicAdd(&Ksum[b * DD + m], s);
        }
}

// ---- KX[b][m][c] += sum_nn Kb[m][nn]*x[c][nn]  (MFMA, no LDS, split-K atomics)
//      n-chunk 128 (was 256): 1024 blocks = 4/CU for latency hiding ----
__global__ __launch_bounds__(256) void k_kx(const __hip_bfloat16* __restrict__ Kb,
                                            const float* __restrict__ x,
                                            float* __restrict__ KX) {
    int b = blockIdx.z;
    int n0 = blockIdx.y * 128;                // 32 n-chunks
    int c0 = blockIdx.x * 256;                // 2 c-halves
    int wave = threadIdx.x >> 6, lane = threadIdx.x & 63;
    int cw = c0 + wave * 64;                  // wave owns 64 c-cols
    int l16 = lane & 15, g = lane >> 4;

    f32x4 acc[4][4] = {};                     // [mi][cj]
    const __hip_bfloat16* kp = Kb + (size_t)b * DD * NN;
    const float* xp = x + (size_t)b * CC * NN;

#pragma unroll
    for (int ks = 0; ks < 4; ++ks) {          // 128 n in steps of 32
        int nk = n0 + ks * 32 + g * 8;
        short8 af[4];
#pragma unroll
        for (int mi = 0; mi < 4; ++mi)
            af[mi] = *reinterpret_cast<const short8*>(kp + (size_t)(mi * 16 + l16) * NN + nk);
        short8 bf[4];
#pragma unroll
        for (int cj = 0; cj < 4; ++cj) {
            const float* xr = xp + (size_t)(cw + cj * 16 + l16) * NN + nk;
            f32x4 lo = *reinterpret_cast<const f32x4*>(xr);
            f32x4 hi = *reinterpret_cast<const f32x4*>(xr + 4);
            short8 v;
#pragma unroll
            for (int e = 0; e < 4; ++e) { v[e] = bf16s(lo[e]); v[4 + e] = bf16s(hi[e]); }
            bf[cj] = v;
        }
#pragma unroll
        for (int mi = 0; mi < 4; ++mi)
#pragma unroll
            for (int cj = 0; cj < 4; ++cj)
                acc[mi][cj] = __builtin_amdgcn_mfma_f32_16x16x32_bf16(af[mi], bf[cj], acc[mi][cj], 0, 0, 0);
    }
#pragma unroll
    for (int mi = 0; mi < 4; ++mi)
#pragma unroll
        for (int cj = 0; cj < 4; ++cj)
#pragma unroll
            for (int r = 0; r < 4; ++r) {
                int m = mi * 16 + 4 * g + r;
                int c = cw + cj * 16 + l16;
                atomicAdd(&KX[((size_t)(b * DD + m)) * CC + c], acc[mi][cj][r]);
            }
}

// ---- KVTb[b][c][m] = sum_cp KX[b][m][cp]*Wv[c][cp] + bv[c]*Ksum[b][m]
//      MFMA, no LDS, split hi/lo bf16 for ~fp32 accuracy.
//      1-wave blocks, 512 blocks = 2/CU (was 128 = 0.5/CU) ----
__global__ __launch_bounds__(64) void k_kv(const float* __restrict__ KX,
                                           const float* __restrict__ Wv,
                                           const float* __restrict__ bv,
                                           const float* __restrict__ Ksum,
                                           __hip_bfloat16* __restrict__ KVTb) {
    int b = blockIdx.y;
    int cw = blockIdx.x * 16;                 // block = 1 wave owns 16 c-rows, all 64 m
    int lane = threadIdx.x & 63;
    int l16 = lane & 15, g = lane >> 4;

    f32x4 acc[4] = {};                        // [mj]
    const float* wvp = Wv + (size_t)(cw + l16) * CC;
    const float* kxp = KX + (size_t)b * DD * CC;

#pragma unroll
    for (int ck = 0; ck < 16; ++ck) {         // 512 cp in steps of 32
        int cp = ck * 32 + g * 8;
        f32x4 w0 = *reinterpret_cast<const f32x4*>(wvp + cp);
        f32x4 w1 = *reinterpret_cast<const f32x4*>(wvp + cp + 4);
        short8 a_hi, a_lo;
#pragma unroll
        for (int e = 0; e < 4; ++e) {
            a_hi[e] = bf16s(w0[e]);     a_lo[e] = bf16s(w0[e] - sbf16(a_hi[e]));
            a_hi[4 + e] = bf16s(w1[e]); a_lo[4 + e] = bf16s(w1[e] - sbf16(a_hi[4 + e]));
        }
#pragma unroll
        for (int mj = 0; mj < 4; ++mj) {
            const float* kr = kxp + (size_t)(mj * 16 + l16) * CC + cp;
            f32x4 k0 = *reinterpret_cast<const f32x4*>(kr);
            f32x4 k1 = *reinterpret_cast<const f32x4*>(kr + 4);
            short8 b_hi, b_lo;
#pragma unroll
            for (int e = 0; e < 4; ++e) {
                b_hi[e] = bf16s(k0[e]);     b_lo[e] = bf16s(k0[e] - sbf16(b_hi[e]));
                b_hi[4 + e] = bf16s(k1[e]); b_lo[4 + e] = bf16s(k1[e] - sbf16(b_hi[4 + e]));
            }
            acc[mj] = __builtin_amdgcn_mfma_f32_16x16x32_bf16(a_hi, b_hi, acc[mj], 0, 0, 0);
            acc[mj] = __builtin_amdgcn_mfma_f32_16x16x32_bf16(a_lo, b_hi, acc[mj], 0, 0, 0);
            acc[mj] = __builtin_amdgcn_mfma_f32_16x16x32_bf16(a_hi, b_lo, acc[mj], 0, 0, 0);
        }
    }
#pragma unroll
    for (int mj = 0; mj < 4; ++mj)
#pragma unroll
        for (int r = 0; r < 4; ++r) {
            int c = cw + 4 * g + r;
            int m = mj * 16 + l16;
            KVTb[((size_t)b * CC + c) * DD + m] =
                __float2bfloat16(acc[mj][r] + bv[c] * Ksum[b * DD + m]);
        }
}

// ---- out[c][n] = x + (gamma/dot(Q[n],Ksum+eps)) * sum_m KVT[c][m]*Q[n][m]
//      MFMA K=64, norm fused in-register ----
__global__ __launch_bounds__(256) void k_out(const float* __restrict__ x,
                                             const __hip_bfloat16* __restrict__ Qb,
                                             const __hip_bfloat16* __restrict__ KVTb,
                                             const float* __restrict__ Ksum,
                                             const float* __restrict__ gamma,
                                             float* __restrict__ out) {
    int b = blockIdx.z;
    int c_blk = blockIdx.x * 128, n_blk = blockIdx.y * 128;
    int wave = threadIdx.x >> 6, lane = threadIdx.x & 63;
    int cw = c_blk + (wave >> 1) * 64, nw = n_blk + (wave & 1) * 64;
    int l16 = lane & 15, g = lane >> 4;

    float ksv[2][8];
#pragma unroll
    for (int ck = 0; ck < 2; ++ck)
#pragma unroll
        for (int e = 0; e < 8; ++e)
            ksv[ck][e] = Ksum[b * DD + (ck * 4 + g) * 8 + e] + EPSV;

    f32x4 acc[4][4] = {};
    float dot[4] = {0.f, 0.f, 0.f, 0.f};
    const short8* ap = reinterpret_cast<const short8*>(KVTb) + ((size_t)b * CC + cw) * 8;
    const short8* bp = reinterpret_cast<const short8*>(Qb) + ((size_t)b * NN + nw) * 8;
#pragma unroll
    for (int ck = 0; ck < 2; ++ck) {
        int ch = ck * 4 + g;
        short8 af[4], bf[4];
#pragma unroll
        for (int i = 0; i < 4; ++i) af[i] = ap[(size_t)(i * 16 + l16) * 8 + ch];
#pragma unroll
        for (int i = 0; i < 4; ++i) bf[i] = bp[(size_t)(i * 16 + l16) * 8 + ch];
#pragma unroll
        for (int j = 0; j < 4; ++j)
#pragma unroll
            for (int e = 0; e < 8; ++e)
                dot[j] = fmaf(sbf16(bf[j][e]), ksv[ck][e], dot[j]);
#pragma unroll
        for (int i = 0; i < 4; ++i)
#pragma unroll
            for (int j = 0; j < 4; ++j)
                acc[i][j] = __builtin_amdgcn_mfma_f32_16x16x32_bf16(af[i], bf[j], acc[i][j], 0, 0, 0);
    }
    float gm = gamma[0];
    float sc[4];
#pragma unroll
    for (int j = 0; j < 4; ++j) {
        float d = dot[j];
        d += __shfl_xor(d, 16, 64);
        d += __shfl_xor(d, 32, 64);
        sc[j] = gm / d;
    }
    const float* xb = x + (size_t)b * CC * NN;
    float* ob = out + (size_t)b * CC * NN;
#pragma unroll
    for (int i = 0; i < 4; ++i)
#pragma unroll
        for (int r = 0; r < 4; ++r) {
            int c = cw + i * 16 + 4 * g + r;
            size_t rowoff = (size_t)c * NN;
#pragma unroll
            for (int j = 0; j < 4; ++j) {
                int n = nw + j * 16 + l16;
                ob[rowoff + n] = xb[rowoff + n] + sc[j] * acc[i][j][r];
            }
        }
}

extern "C" void kernel_launch(void* const* d_in, const int* in_sizes, int n_in,
                              void* d_out, int out_size, void* d_ws, size_t ws_size,
                              hipStream_t stream) {
    const float* x     = (const float*)d_in[0];
    const float* Wq    = (const float*)d_in[1];
    const float* bq    = (const float*)d_in[2];
    const float* Wk    = (const float*)d_in[3];
    const float* bk    = (const float*)d_in[4];
    const float* Wv    = (const float*)d_in[5];
    const float* bv    = (const float*)d_in[6];
    const float* gamma = (const float*)d_in[7];
    float* out = (float*)d_out;

    float* ws    = (float*)d_ws;
    float* KX    = ws;                                   // B*D*C fp32 (2MB)
    float* Ksum  = KX + (size_t)BB * DD * CC;            // B*D fp32
    __hip_bfloat16* Qb   = (__hip_bfloat16*)(Ksum + BB * DD);  // B*N*D bf16
    __hip_bfloat16* Kb   = Qb + (size_t)BB * NN * DD;    // B*D*N bf16
    __hip_bfloat16* KVTb = Kb + (size_t)BB * DD * NN;    // B*C*D bf16
    __hip_bfloat16* Wcat = KVTb + (size_t)BB * CC * DD;  // 128*C bf16

    k_prep<<<dim3(769), dim3(256), 0, stream>>>(Wq, Wk, Wcat, KX, Ksum);
    k_proj<<<dim3(NN / 128, BB), dim3(256), 0, stream>>>(x, Wcat, bq, bk, Qb, Kb, Ksum);
    k_kx<<<dim3(2, 32, BB), dim3(256), 0, stream>>>(Kb, x, KX);
    k_kv<<<dim3(CC / 16, BB), dim3(64), 0, stream>>>(KX, Wv, bv, Ksum, KVTb);
    k_out<<<dim3(CC / 128, NN / 128, BB), dim3(256), 0, stream>>>(x, Qb, KVTb, Ksum, gamma, out);
}

// Round 15
// 197.884 us; speedup vs baseline: 1.4164x; 1.1046x over previous
//
#include <hip/hip_runtime.h>
#include <hip/hip_bf16.h>
#include <math.h>

#define BB 16
#define CC 512
#define DD 64
#define NN 4096
#define EPSV 1e-6f

typedef __attribute__((ext_vector_type(8))) short short8;
typedef __attribute__((ext_vector_type(4))) short s16x4;
typedef __attribute__((ext_vector_type(4))) float f32x4;

__device__ __forceinline__ float softplus_f(float v) {
    return fmaxf(v, 0.0f) + log1pf(expf(-fabsf(v)));
}
__device__ __forceinline__ short bf16s(float f) {
    __hip_bfloat16 h = __float2bfloat16(f);
    return __builtin_bit_cast(short, h);
}
__device__ __forceinline__ float sbf16(short s) {
    return __bfloat162float(__builtin_bit_cast(__hip_bfloat16, s));
}

// ---- prep: Wcat bf16 [128][512] (blocks 0-255), zero KX (256-767), zero Ksum (768) ----
__global__ __launch_bounds__(256) void k_prep(const float* __restrict__ Wq,
                                              const float* __restrict__ Wk,
                                              __hip_bfloat16* __restrict__ Wcat,
                                              float* __restrict__ KX,
                                              float* __restrict__ Ksum) {
    int blk = blockIdx.x;
    if (blk < 256) {
        int i = blk * 256 + threadIdx.x;
        int j = i >> 9, c = i & 511;
        float v = (j < DD) ? Wq[j * CC + c] : Wk[(j - DD) * CC + c];
        Wcat[i] = __float2bfloat16(v);
    } else if (blk < 768) {
        int i = (blk - 256) * 256 + threadIdx.x;   // 512*256 f32x4 = 2MB
        f32x4 z = {0.f, 0.f, 0.f, 0.f};
        reinterpret_cast<f32x4*>(KX)[i] = z;
    } else {
        f32x4 z = {0.f, 0.f, 0.f, 0.f};
        reinterpret_cast<f32x4*>(Ksum)[threadIdx.x] = z;  // 1024 floats
    }
}

// ---- Q/K projection via MFMA, x staged through LDS (fused transpose, double-buffered).
//      r6 structure + RELAXED BARRIER: lgkmcnt(0)+s_barrier only (no vmcnt drain),
//      so the issued-early global prefetch survives the barrier (T4-minimum).
//      Also accumulates Ksum[b][m]. Qb[b][n][d] bf16 ; Kb[b][m][n] bf16 ----
__global__ __launch_bounds__(256) void k_proj(const float* __restrict__ x,
                                              const __hip_bfloat16* __restrict__ Wcat,
                                              const float* __restrict__ bq,
                                              const float* __restrict__ bk,
                                              __hip_bfloat16* __restrict__ Qb,
                                              __hip_bfloat16* __restrict__ Kb,
                                              float* __restrict__ Ksum) {
    // xs: 32-c chunk of x, bf16, [c][n] rows padded to 132 u16 (264 B)
    // ws: 32-c chunk of Wcat, bf16, [j][c] rows padded to 40 u16 (80 B)
    __shared__ unsigned short xs[2][32][132];
    __shared__ unsigned short ws[2][128][40];

    int b = blockIdx.y;
    int n_blk = blockIdx.x * 128;
    int t = threadIdx.x;
    int wave = t >> 6, lane = t & 63;
    int nwl = wave * 32;                    // wave's local n base
    int n_wave = n_blk + nwl;
    int l16 = lane & 15, g = lane >> 4;

    // staging assignments
    int sv = t & 31;                        // x: 4-float group along n
    int sc = t >> 5;                        // x: base c-row (0..7), rows sc+8i
    int wj = t >> 1;                        // W: row j (0..127)
    int wh = t & 1;                         // W: 16-elem half of the 32-c chunk

    const float* xb = x + (size_t)b * CC * NN + n_blk + sv * 4;
    const unsigned short* wg = reinterpret_cast<const unsigned short*>(Wcat)
                               + (size_t)wj * 512 + wh * 16;

    f32x4 xr[4];
    s16x4 wr[4];

    auto loadx = [&](int c0) {
#pragma unroll
        for (int i = 0; i < 4; ++i)
            xr[i] = *reinterpret_cast<const f32x4*>(xb + (size_t)(c0 + sc + i * 8) * NN);
    };
    auto loadw = [&](int c0) {
#pragma unroll
        for (int k = 0; k < 4; ++k)
            wr[k] = *reinterpret_cast<const s16x4*>(wg + c0 + k * 4);
    };
    auto writex = [&](int bi) {
#pragma unroll
        for (int i = 0; i < 4; ++i) {
            s16x4 pv;
#pragma unroll
            for (int j = 0; j < 4; ++j) pv[j] = bf16s(xr[i][j]);
            *reinterpret_cast<s16x4*>(&xs[bi][sc + i * 8][sv * 4]) = pv;
        }
    };
    auto writew = [&](int bi) {
#pragma unroll
        for (int k = 0; k < 4; ++k)
            *reinterpret_cast<s16x4*>(&ws[bi][wj][wh * 16 + k * 4]) = wr[k];
    };

    f32x4 accQ[2][4] = {};                  // Q: D[n][j]
    f32x4 accK[4][2] = {};                  // K: D[j][n]

    loadx(0); loadw(0);
    writex(0); writew(0);

    for (int ck = 0; ck < 16; ++ck) {
        int cur = ck & 1;
        if (ck < 15) { loadx((ck + 1) * 32); loadw((ck + 1) * 32); }  // prefetch (stays in flight)
        // relaxed barrier: drain LDS ops only; global loads keep flying across it
        asm volatile("s_waitcnt lgkmcnt(0)" ::: "memory");
        __builtin_amdgcn_s_barrier();
        short8 xf[2], wf[8];
#pragma unroll
        for (int nf = 0; nf < 2; ++nf) {
            short8 v;
#pragma unroll
            for (int e = 0; e < 8; ++e)
                v[e] = (short)xs[cur][g * 8 + e][nwl + nf * 16 + l16];
            xf[nf] = v;
        }
#pragma unroll
        for (int jf = 0; jf < 8; ++jf)
            wf[jf] = *reinterpret_cast<const short8*>(&ws[cur][jf * 16 + l16][g * 8]);
#pragma unroll
        for (int nf = 0; nf < 2; ++nf)
#pragma unroll
            for (int jf = 0; jf < 4; ++jf)
                accQ[nf][jf] = __builtin_amdgcn_mfma_f32_16x16x32_bf16(xf[nf], wf[jf], accQ[nf][jf], 0, 0, 0);
#pragma unroll
        for (int jf = 0; jf < 4; ++jf)
#pragma unroll
            for (int nf = 0; nf < 2; ++nf)
                accK[jf][nf] = __builtin_amdgcn_mfma_f32_16x16x32_bf16(wf[4 + jf], xf[nf], accK[jf][nf], 0, 0, 0);
        if (ck < 15) { writex(cur ^ 1); writew(cur ^ 1); }   // vmcnt waited here (by use), not at barrier
    }

    // Q epilogue: row n = n_wave + nf*16 + 4g + r, col j = jf*16 + l16
#pragma unroll
    for (int nf = 0; nf < 2; ++nf)
#pragma unroll
        for (int jf = 0; jf < 4; ++jf)
#pragma unroll
            for (int r = 0; r < 4; ++r) {
                int n = n_wave + nf * 16 + 4 * g + r;
                int j = jf * 16 + l16;
                float v = softplus_f(accQ[nf][jf][r] + bq[j]);
                Qb[((size_t)b * NN + n) * DD + j] = __float2bfloat16(v);
            }
    // K epilogue: row m = jf*16 + 4g + r, col n = n_wave + nf*16 + l16; fused Ksum
#pragma unroll
    for (int jf = 0; jf < 4; ++jf)
#pragma unroll
        for (int r = 0; r < 4; ++r) {
            int m = jf * 16 + 4 * g + r;
            float s = 0.f;
#pragma unroll
            for (int nf = 0; nf < 2; ++nf) {
                int n = n_wave + nf * 16 + l16;
                float v = softplus_f(accK[jf][nf][r] + bk[m]);
                Kb[((size_t)b * DD + m) * NN + n] = __float2bfloat16(v);
                s += v;
            }
            s += __shfl_xor(s, 1, 64);
            s += __shfl_xor(s, 2, 64);
            s += __shfl_xor(s, 4, 64);
            s += __shfl_xor(s, 8, 64);
            if (l16 == 0) atomicAdd(&Ksum[b * DD + m], s);
        }
}

// ---- KX[b][m][c] += sum_nn Kb[m][nn]*x[c][nn]  (MFMA, no LDS, split-K atomics)
//      r6 grid (2,16,BB): measured-best ----
__global__ __launch_bounds__(256) void k_kx(const __hip_bfloat16* __restrict__ Kb,
                                            const float* __restrict__ x,
                                            float* __restrict__ KX) {
    int b = blockIdx.z;
    int n0 = blockIdx.y * 256;                // 16 n-chunks
    int c0 = blockIdx.x * 256;                // 2 c-halves
    int wave = threadIdx.x >> 6, lane = threadIdx.x & 63;
    int cw = c0 + wave * 64;                  // wave owns 64 c-cols
    int l16 = lane & 15, g = lane >> 4;

    f32x4 acc[4][4] = {};                     // [mi][cj]
    const __hip_bfloat16* kp = Kb + (size_t)b * DD * NN;
    const float* xp = x + (size_t)b * CC * NN;

#pragma unroll
    for (int ks = 0; ks < 8; ++ks) {          // 256 n in steps of 32
        int nk = n0 + ks * 32 + g * 8;
        short8 af[4];
#pragma unroll
        for (int mi = 0; mi < 4; ++mi)
            af[mi] = *reinterpret_cast<const short8*>(kp + (size_t)(mi * 16 + l16) * NN + nk);
        short8 bf[4];
#pragma unroll
        for (int cj = 0; cj < 4; ++cj) {
            const float* xr = xp + (size_t)(cw + cj * 16 + l16) * NN + nk;
            f32x4 lo = *reinterpret_cast<const f32x4*>(xr);
            f32x4 hi = *reinterpret_cast<const f32x4*>(xr + 4);
            short8 v;
#pragma unroll
            for (int e = 0; e < 4; ++e) { v[e] = bf16s(lo[e]); v[4 + e] = bf16s(hi[e]); }
            bf[cj] = v;
        }
#pragma unroll
        for (int mi = 0; mi < 4; ++mi)
#pragma unroll
            for (int cj = 0; cj < 4; ++cj)
                acc[mi][cj] = __builtin_amdgcn_mfma_f32_16x16x32_bf16(af[mi], bf[cj], acc[mi][cj], 0, 0, 0);
    }
#pragma unroll
    for (int mi = 0; mi < 4; ++mi)
#pragma unroll
        for (int cj = 0; cj < 4; ++cj)
#pragma unroll
            for (int r = 0; r < 4; ++r) {
                int m = mi * 16 + 4 * g + r;
                int c = cw + cj * 16 + l16;
                atomicAdd(&KX[((size_t)(b * DD + m)) * CC + c], acc[mi][cj][r]);
            }
}

// ---- KVTb[b][c][m] = sum_cp KX[b][m][cp]*Wv[c][cp] + bv[c]*Ksum[b][m]
//      MFMA, no LDS, split hi/lo bf16 for ~fp32 accuracy. r6 grid: measured-best ----
__global__ __launch_bounds__(256) void k_kv(const float* __restrict__ KX,
                                            const float* __restrict__ Wv,
                                            const float* __restrict__ bv,
                                            const float* __restrict__ Ksum,
                                            __hip_bfloat16* __restrict__ KVTb) {
    int b = blockIdx.y;
    int c0 = blockIdx.x * 64;
    int wave = threadIdx.x >> 6, lane = threadIdx.x & 63;
    int cw = c0 + wave * 16;                  // wave owns 16 c-rows, all 64 m
    int l16 = lane & 15, g = lane >> 4;

    f32x4 acc[4] = {};                        // [mj]
    const float* wvp = Wv + (size_t)(cw + l16) * CC;
    const float* kxp = KX + (size_t)b * DD * CC;

#pragma unroll
    for (int ck = 0; ck < 16; ++ck) {         // 512 cp in steps of 32
        int cp = ck * 32 + g * 8;
        f32x4 w0 = *reinterpret_cast<const f32x4*>(wvp + cp);
        f32x4 w1 = *reinterpret_cast<const f32x4*>(wvp + cp + 4);
        short8 a_hi, a_lo;
#pragma unroll
        for (int e = 0; e < 4; ++e) {
            a_hi[e] = bf16s(w0[e]);     a_lo[e] = bf16s(w0[e] - sbf16(a_hi[e]));
            a_hi[4 + e] = bf16s(w1[e]); a_lo[4 + e] = bf16s(w1[e] - sbf16(a_hi[4 + e]));
        }
#pragma unroll
        for (int mj = 0; mj < 4; ++mj) {
            const float* kr = kxp + (size_t)(mj * 16 + l16) * CC + cp;
            f32x4 k0 = *reinterpret_cast<const f32x4*>(kr);
            f32x4 k1 = *reinterpret_cast<const f32x4*>(kr + 4);
            short8 b_hi, b_lo;
#pragma unroll
            for (int e = 0; e < 4; ++e) {
                b_hi[e] = bf16s(k0[e]);     b_lo[e] = bf16s(k0[e] - sbf16(b_hi[e]));
                b_hi[4 + e] = bf16s(k1[e]); b_lo[4 + e] = bf16s(k1[e] - sbf16(b_hi[4 + e]));
            }
            acc[mj] = __builtin_amdgcn_mfma_f32_16x16x32_bf16(a_hi, b_hi, acc[mj], 0, 0, 0);
            acc[mj] = __builtin_amdgcn_mfma_f32_16x16x32_bf16(a_lo, b_hi, acc[mj], 0, 0, 0);
            acc[mj] = __builtin_amdgcn_mfma_f32_16x16x32_bf16(a_hi, b_lo, acc[mj], 0, 0, 0);
        }
    }
#pragma unroll
    for (int mj = 0; mj < 4; ++mj)
#pragma unroll
        for (int r = 0; r < 4; ++r) {
            int c = cw + 4 * g + r;
            int m = mj * 16 + l16;
            KVTb[((size_t)b * CC + c) * DD + m] =
                __float2bfloat16(acc[mj][r] + bv[c] * Ksum[b * DD + m]);
        }
}

// ---- out[c][n] = x + (gamma/dot(Q[n],Ksum+eps)) * sum_m KVT[c][m]*Q[n][m]
//      MFMA K=64, norm fused in-register ----
__global__ __launch_bounds__(256) void k_out(const float* __restrict__ x,
                                             const __hip_bfloat16* __restrict__ Qb,
                                             const __hip_bfloat16* __restrict__ KVTb,
                                             const float* __restrict__ Ksum,
                                             const float* __restrict__ gamma,
                                             float* __restrict__ out) {
    int b = blockIdx.z;
    int c_blk = blockIdx.x * 128, n_blk = blockIdx.y * 128;
    int wave = threadIdx.x >> 6, lane = threadIdx.x & 63;
    int cw = c_blk + (wave >> 1) * 64, nw = n_blk + (wave & 1) * 64;
    int l16 = lane & 15, g = lane >> 4;

    float ksv[2][8];
#pragma unroll
    for (int ck = 0; ck < 2; ++ck)
#pragma unroll
        for (int e = 0; e < 8; ++e)
            ksv[ck][e] = Ksum[b * DD + (ck * 4 + g) * 8 + e] + EPSV;

    f32x4 acc[4][4] = {};
    float dot[4] = {0.f, 0.f, 0.f, 0.f};
    const short8* ap = reinterpret_cast<const short8*>(KVTb) + ((size_t)b * CC + cw) * 8;
    const short8* bp = reinterpret_cast<const short8*>(Qb) + ((size_t)b * NN + nw) * 8;
#pragma unroll
    for (int ck = 0; ck < 2; ++ck) {
        int ch = ck * 4 + g;
        short8 af[4], bf[4];
#pragma unroll
        for (int i = 0; i < 4; ++i) af[i] = ap[(size_t)(i * 16 + l16) * 8 + ch];
#pragma unroll
        for (int i = 0; i < 4; ++i) bf[i] = bp[(size_t)(i * 16 + l16) * 8 + ch];
#pragma unroll
        for (int j = 0; j < 4; ++j)
#pragma unroll
            for (int e = 0; e < 8; ++e)
                dot[j] = fmaf(sbf16(bf[j][e]), ksv[ck][e], dot[j]);
#pragma unroll
        for (int i = 0; i < 4; ++i)
#pragma unroll
            for (int j = 0; j < 4; ++j)
                acc[i][j] = __builtin_amdgcn_mfma_f32_16x16x32_bf16(af[i], bf[j], acc[i][j], 0, 0, 0);
    }
    float gm = gamma[0];
    float sc[4];
#pragma unroll
    for (int j = 0; j < 4; ++j) {
        float d = dot[j];
        d += __shfl_xor(d, 16, 64);
        d += __shfl_xor(d, 32, 64);
        sc[j] = gm / d;
    }
    const float* xb = x + (size_t)b * CC * NN;
    float* ob = out + (size_t)b * CC * NN;
#pragma unroll
    for (int i = 0; i < 4; ++i)
#pragma unroll
        for (int r = 0; r < 4; ++r) {
            int c = cw + i * 16 + 4 * g + r;
            size_t rowoff = (size_t)c * NN;
#pragma unroll
            for (int j = 0; j < 4; ++j) {
                int n = nw + j * 16 + l16;
                ob[rowoff + n] = xb[rowoff + n] + sc[j] * acc[i][j][r];
            }
        }
}

extern "C" void kernel_launch(void* const* d_in, const int* in_sizes, int n_in,
                              void* d_out, int out_size, void* d_ws, size_t ws_size,
                              hipStream_t stream) {
    const float* x     = (const float*)d_in[0];
    const float* Wq    = (const float*)d_in[1];
    const float* bq    = (const float*)d_in[2];
    const float* Wk    = (const float*)d_in[3];
    const float* bk    = (const float*)d_in[4];
    const float* Wv    = (const float*)d_in[5];
    const float* bv    = (const float*)d_in[6];
    const float* gamma = (const float*)d_in[7];
    float* out = (float*)d_out;

    float* ws    = (float*)d_ws;
    float* KX    = ws;                                   // B*D*C fp32 (2MB)
    float* Ksum  = KX + (size_t)BB * DD * CC;            // B*D fp32
    __hip_bfloat16* Qb   = (__hip_bfloat16*)(Ksum + BB * DD);  // B*N*D bf16
    __hip_bfloat16* Kb   = Qb + (size_t)BB * NN * DD;    // B*D*N bf16
    __hip_bfloat16* KVTb = Kb + (size_t)BB * DD * NN;    // B*C*D bf16
    __hip_bfloat16* Wcat = KVTb + (size_t)BB * CC * DD;  // 128*C bf16

    k_prep<<<dim3(769), dim3(256), 0, stream>>>(Wq, Wk, Wcat, KX, Ksum);
    k_proj<<<dim3(NN / 128, BB), dim3(256), 0, stream>>>(x, Wcat, bq, bk, Qb, Kb, Ksum);
    k_kx<<<dim3(2, 16, BB), dim3(256), 0, stream>>>(Kb, x, KX);
    k_kv<<<dim3(CC / 64, BB), dim3(256), 0, stream>>>(KX, Wv, bv, Ksum, KVTb);
    k_out<<<dim3(CC / 128, NN / 128, BB), dim3(256), 0, stream>>>(x, Qb, KVTb, Ksum, gamma, out);
}